// Round 5
// baseline (1402.498 us; speedup 1.0000x reference)
//
#include <hip/hip_runtime.h>
#include <hip/hip_bf16.h>
#include <cstdint>
#include <cstddef>

#define NN   100000
#define EE   1600000
#define FIN  512
#define HID  128
#define CC   40
#define KORD 10

typedef __attribute__((ext_vector_type(4))) float f4;
typedef __attribute__((ext_vector_type(8))) short short8_t;
typedef __attribute__((ext_vector_type(4))) unsigned int u4;

__device__ __forceinline__ unsigned short cvt_bf16(float f) {
  union { float f; unsigned u; } a; a.f = f;
  unsigned r = a.u + 0x7fffu + ((a.u >> 16) & 1u);   // RNE
  return (unsigned short)(r >> 16);
}
__device__ __forceinline__ unsigned pk_bf(float a, float b) {
  union { float f; unsigned u; } x, y; x.f = a; y.f = b;
  unsigned ra = x.u + 0x7fffu + ((x.u >> 16) & 1u);
  unsigned rb = y.u + 0x7fffu + ((y.u >> 16) & 1u);
  return (ra >> 16) | (rb & 0xffff0000u);
}
// two packed-bf16 words -> 4 floats
__device__ __forceinline__ f4 cvf2(unsigned lo, unsigned hi) {
  union { unsigned u; float f; } a, b, c, d;
  a.u = lo << 16; b.u = lo & 0xffff0000u;
  c.u = hi << 16; d.u = hi & 0xffff0000u;
  f4 r; r.x = a.f; r.y = b.f; r.z = c.f; r.w = d.f; return r;
}

// ---------------- deg count (blocks [0,ndeg)) || W1 bf16 k-tiled transpose ----------------
__global__ __launch_bounds__(256) void k_dw(const int* __restrict__ rowI, int* __restrict__ deg,
                                            const float* __restrict__ W1, unsigned short* __restrict__ W1T,
                                            int ndeg) {
  int b = blockIdx.x;
  if (b < ndeg) {
    int i = b * 256 + threadIdx.x;
    if (i < EE) atomicAdd(&deg[rowI[i]], 1);
  } else {
    int idx = (b - ndeg) * 256 + threadIdx.x;   // 0..65535
    int k = idx >> 7, n = idx & 127;
    W1T[(k >> 5) * 4096 + n * 32 + (k & 31)] = cvt_bf16(W1[idx]);
  }
}

// deg+=1 (self loop); dis/sqd/invd; degree histogram for counting sort
__global__ __launch_bounds__(256) void k_finalize(int* __restrict__ deg, float* __restrict__ dis,
                                                  float* __restrict__ sqd, float* __restrict__ invd,
                                                  int* __restrict__ hist) {
  int i = blockIdx.x * 256 + threadIdx.x;
  if (i < NN) {
    int d = deg[i] + 1;
    deg[i] = d;
    float fd = (float)d;
    dis[i]  = rsqrtf(fd);
    sqd[i]  = sqrtf(fd);
    invd[i] = 1.0f / fd;
    atomicAdd(&hist[min(d, 255)], 1);
  }
}

// ---------------- exclusive scan over deg ----------------
__global__ __launch_bounds__(256) void k_scan1(const int* __restrict__ cnt, int* __restrict__ excl,
                                               int* __restrict__ bsums) {
  __shared__ int s[256];
  int tid = threadIdx.x;
  int base = blockIdx.x * 1024 + tid * 4;
  int v0 = (base + 0 < NN) ? cnt[base + 0] : 0;
  int v1 = (base + 1 < NN) ? cnt[base + 1] : 0;
  int v2 = (base + 2 < NN) ? cnt[base + 2] : 0;
  int v3 = (base + 3 < NN) ? cnt[base + 3] : 0;
  int tsum = v0 + v1 + v2 + v3;
  s[tid] = tsum;
  __syncthreads();
  for (int off = 1; off < 256; off <<= 1) {
    int t = (tid >= off) ? s[tid - off] : 0;
    __syncthreads();
    if (tid >= off) s[tid] += t;
    __syncthreads();
  }
  int run = s[tid] - tsum;
  if (tid == 255) bsums[blockIdx.x] = s[255];
  if (base + 0 < NN) excl[base + 0] = run; run += v0;
  if (base + 1 < NN) excl[base + 1] = run; run += v1;
  if (base + 2 < NN) excl[base + 2] = run; run += v2;
  if (base + 3 < NN) excl[base + 3] = run;
}

// block0: scan block sums ; block1: exclusive scan hist (in place)
__global__ __launch_bounds__(256) void k_scan2h(int* __restrict__ bsums, int nb, int* __restrict__ hist) {
  __shared__ int s[256];
  int tid = threadIdx.x;
  if (blockIdx.x == 0) {
    int v = (tid < nb) ? bsums[tid] : 0;
    s[tid] = v;
    __syncthreads();
    for (int off = 1; off < 256; off <<= 1) {
      int t = (tid >= off) ? s[tid - off] : 0;
      __syncthreads();
      if (tid >= off) s[tid] += t;
      __syncthreads();
    }
    if (tid < nb) bsums[tid] = s[tid] - v;
  } else {
    int v = hist[tid];
    s[tid] = v;
    __syncthreads();
    for (int off = 1; off < 256; off <<= 1) {
      int t = (tid >= off) ? s[tid - off] : 0;
      __syncthreads();
      if (tid >= off) s[tid] += t;
      __syncthreads();
    }
    hist[tid] = s[tid] - v;
  }
}

// blocks [0,nb3): finish scan (rs, cur) ; blocks [nb3,2*nb3): degree-sort perm
__global__ __launch_bounds__(256) void k_scan3p(const int* __restrict__ cnt, int* __restrict__ rs,
                                                int* __restrict__ cur, const int* __restrict__ bsums,
                                                const int* __restrict__ hoff, int* __restrict__ hcnt,
                                                int* __restrict__ perm, int nb3) {
  int b = blockIdx.x;
  int tid = threadIdx.x;
  if (b < nb3) {
    int i = b * 256 + tid;
    if (i < NN) {
      int v = rs[i] + bsums[i >> 10];
      rs[i] = v;
      cur[i] = v;
      if (i == NN - 1) rs[NN] = v + cnt[i];
    }
  } else {
    int i = (b - nb3) * 256 + tid;
    if (i < NN) {
      int d = min(cnt[i], 255);
      int pos = hoff[d] + atomicAdd(&hcnt[d], 1);
      perm[pos] = i;
    }
  }
}

// ---------------- merged: GEMM1 (blocks [0,ng1)) || CSR scatter ----------------
#define LDK 40
__global__ __launch_bounds__(256) void k_g1sc(const float* __restrict__ x, const unsigned short* __restrict__ W1T,
                                              const float* __restrict__ b1, float* __restrict__ h1,
                                              const int* __restrict__ rowI, const int* __restrict__ colI,
                                              int* __restrict__ cur, int* __restrict__ colS, int ng1) {
  __shared__ __align__(16) short As_s[128][LDK];
  __shared__ __align__(16) short Bs_s[128][LDK];
  if (blockIdx.x >= ng1) {
    // ---- scatter: 1024 edges per block ----
    int bid = blockIdx.x - ng1;
#pragma unroll
    for (int t = 0; t < 4; ++t) {
      int i = bid * 1024 + t * 256 + threadIdx.x;
      if (i < EE + NN) {
        int r, c;
        if (i < EE) { r = rowI[i]; c = colI[i]; }
        else        { r = i - EE;  c = r; }
        int pos = atomicAdd(&cur[r], 1);
        colS[pos] = c * 80;        // byte offset into bf16 shadow [node][40]
      }
    }
    return;
  }
  // ---- GEMM1: 128x128 tile, K-step 32, MFMA bf16 ----
  int tid  = threadIdx.x;
  int wave = tid >> 6, lane = tid & 63;
  int blockRow = blockIdx.x * 128;
  int wr = (wave & 1) * 64, wc = (wave >> 1) * 64;
  int l15 = lane & 15, lk = (lane >> 4) * 8;
  int ar = tid >> 1, ak = (tid & 1) * 16;

  f4 acc[4][4] = {};

  for (int k0 = 0; k0 < FIN; k0 += 32) {
    int gr = blockRow + ar;
    f4 xv0 = {0.f,0.f,0.f,0.f}, xv1 = xv0, xv2 = xv0, xv3 = xv0;
    if (gr < NN) {
      const float* xr = x + (size_t)gr * FIN + k0 + ak;
      xv0 = *(const f4*)&xr[0];
      xv1 = *(const f4*)&xr[4];
      xv2 = *(const f4*)&xr[8];
      xv3 = *(const f4*)&xr[12];
    }
    short8_t p0, p1;
#pragma unroll
    for (int q = 0; q < 4; ++q) {
      p0[q]     = (short)cvt_bf16(xv0[q]);
      p0[q + 4] = (short)cvt_bf16(xv1[q]);
      p1[q]     = (short)cvt_bf16(xv2[q]);
      p1[q + 4] = (short)cvt_bf16(xv3[q]);
    }
    *(short8_t*)&As_s[ar][ak]     = p0;
    *(short8_t*)&As_s[ar][ak + 8] = p1;

    const unsigned short* Wt = W1T + (k0 >> 5) * 4096;
    short8_t q0 = *(const short8_t*)&Wt[tid * 16];
    short8_t q1 = *(const short8_t*)&Wt[tid * 16 + 8];
    int bn = tid >> 1, bkk = (tid & 1) * 16;
    *(short8_t*)&Bs_s[bn][bkk]     = q0;
    *(short8_t*)&Bs_s[bn][bkk + 8] = q1;

    __syncthreads();

    short8_t afr[4], bfr[4];
#pragma unroll
    for (int m = 0; m < 4; ++m) afr[m] = *(const short8_t*)&As_s[wr + m * 16 + l15][lk];
#pragma unroll
    for (int n = 0; n < 4; ++n) bfr[n] = *(const short8_t*)&Bs_s[wc + n * 16 + l15][lk];
#pragma unroll
    for (int m = 0; m < 4; ++m)
#pragma unroll
      for (int n = 0; n < 4; ++n)
        acc[m][n] = __builtin_amdgcn_mfma_f32_16x16x32_bf16(afr[m], bfr[n], acc[m][n], 0, 0, 0);

    __syncthreads();
  }

  float bias[4];
#pragma unroll
  for (int n = 0; n < 4; ++n) bias[n] = b1[wc + n * 16 + l15];
#pragma unroll
  for (int m = 0; m < 4; ++m) {
    int baseRow = blockRow + wr + m * 16 + (lane >> 4) * 4;
#pragma unroll
    for (int n = 0; n < 4; ++n) {
      int col = wc + n * 16 + l15;
#pragma unroll
      for (int r = 0; r < 4; ++r) {
        int grow = baseRow + r;
        if (grow < NN) h1[(size_t)grow * HID + col] = fmaxf(acc[m][n][r] + bias[n], 0.f);
      }
    }
  }
}

// ---------------- GEMM2: out = temp0*Tx0 ; w0 = Tx0 * dis ----------------
__global__ __launch_bounds__(256) void k_gemm2(const float* __restrict__ h1, const float* __restrict__ W2,
                                               const float* __restrict__ b2, const float* __restrict__ temp,
                                               const float* __restrict__ dis,
                                               float* __restrict__ w0, float* __restrict__ outAcc) {
  __shared__ float sW[HID * CC];
  __shared__ float sb[CC];
  int tid = threadIdx.x;
  for (int i = tid; i < HID * CC; i += 256) sW[i] = W2[i];
  if (tid < CC) sb[tid] = b2[tid];
  __syncthreads();
  int gid = blockIdx.x * 256 + tid;
  int row = gid / CC;
  int col = gid - row * CC;
  const float* hr = h1 + (size_t)row * HID;
  float acc = sb[col];
#pragma unroll 8
  for (int k = 0; k < HID; ++k) acc = fmaf(hr[k], sW[k * CC + col], acc);
  outAcc[gid] = temp[0] * acc;
  w0[gid] = acc * dis[row];
}

// ---------------- f32 -> bf16 shadow convert ----------------
__global__ __launch_bounds__(256) void k_cvt(const float* __restrict__ v, unsigned short* __restrict__ sh) {
  int i = blockIdx.x * 256 + threadIdx.x;
  if (i * 4 >= NN * CC) return;
  f4 t = *(const f4*)&v[i * 4];
  unsigned lo = pk_bf(t.x, t.y), hi = pk_bf(t.z, t.w);
  unsigned long long p = (unsigned long long)lo | ((unsigned long long)hi << 32);
  *(unsigned long long*)&sh[i * 4] = p;
}

// ---------------- propagation: 5 lanes/node (16B bf16 gathers), 12 nodes/wave, degree-sorted ----------------
// MODE 0: w1 = invd*Sum ;              vio = w1
// MODE 1: wk = 2*invd*Sum - vio ;      vio = wk
// both:   shOut = bf16(wk) ; out += temp[kIdx]*sqd*wk
template <int MODE>
__global__ __launch_bounds__(256) void k_prop(const unsigned short* __restrict__ shIn,
                                              unsigned short* __restrict__ shOut,
                                              float* __restrict__ vio,
                                              float* __restrict__ outAcc,
                                              const int* __restrict__ colS,
                                              const int* __restrict__ rs,
                                              const int* __restrict__ perm,
                                              const float* __restrict__ invd, const float* __restrict__ sqd,
                                              const float* __restrict__ temp, int kIdx) {
  int lane = threadIdx.x & 63;
  int wave = threadIdx.x >> 6;
  int grp  = lane / 5;             // 0..12 (12 -> idle lanes 60..63)
  int fi   = lane - grp * 5;       // 0..4 -> features fi*8 .. fi*8+7
  int nidx = blockIdx.x * 48 + wave * 12 + grp;
  bool active = (grp < 12) && (nidx < NN);
  int node = 0, s = 0, e = 0;
  if (active) { node = perm[nidx]; s = rs[node]; e = rs[node + 1]; }
  const char* base = (const char*)shIn + fi * 16;
  f4 lo0 = {0.f,0.f,0.f,0.f}, hi0 = lo0, lo1 = lo0, hi1 = lo0;
  f4 lo2 = lo0, hi2 = lo0, lo3 = lo0, hi3 = lo0;
  int j = s;
  for (; j + 4 <= e; j += 4) {
    int c0 = colS[j], c1 = colS[j + 1], c2 = colS[j + 2], c3 = colS[j + 3];
    u4 p0 = *(const u4*)(base + c0);
    u4 p1 = *(const u4*)(base + c1);
    u4 p2 = *(const u4*)(base + c2);
    u4 p3 = *(const u4*)(base + c3);
    lo0 += cvf2(p0.x, p0.y); hi0 += cvf2(p0.z, p0.w);
    lo1 += cvf2(p1.x, p1.y); hi1 += cvf2(p1.z, p1.w);
    lo2 += cvf2(p2.x, p2.y); hi2 += cvf2(p2.z, p2.w);
    lo3 += cvf2(p3.x, p3.y); hi3 += cvf2(p3.z, p3.w);
  }
  if (j + 2 <= e) {
    int c0 = colS[j], c1 = colS[j + 1];
    u4 p0 = *(const u4*)(base + c0);
    u4 p1 = *(const u4*)(base + c1);
    lo0 += cvf2(p0.x, p0.y); hi0 += cvf2(p0.z, p0.w);
    lo1 += cvf2(p1.x, p1.y); hi1 += cvf2(p1.z, p1.w);
    j += 2;
  }
  if (j < e) {
    u4 p0 = *(const u4*)(base + colS[j]);
    lo2 += cvf2(p0.x, p0.y); hi2 += cvf2(p0.z, p0.w);
  }

  if (active) {
    f4 slo = (lo0 + lo1) + (lo2 + lo3);
    f4 shi = (hi0 + hi1) + (hi2 + hi3);
    float iv = invd[node], sq = sqd[node], tk = temp[kIdx];
    size_t o = (size_t)node * CC + fi * 8;
    f4 wlo, whi;
    if (MODE == 0) { wlo = iv * slo; whi = iv * shi; }
    else {
      f4 plo = *(const f4*)&vio[o];
      f4 phi = *(const f4*)&vio[o + 4];
      wlo = (2.f * iv) * slo - plo;
      whi = (2.f * iv) * shi - phi;
    }
    *(f4*)&vio[o]     = wlo;
    *(f4*)&vio[o + 4] = whi;
    u4 pk;
    pk.x = pk_bf(wlo.x, wlo.y); pk.y = pk_bf(wlo.z, wlo.w);
    pk.z = pk_bf(whi.x, whi.y); pk.w = pk_bf(whi.z, whi.w);
    *(u4*)((char*)shOut + (size_t)node * 80 + fi * 16) = pk;
    f4 olo = *(const f4*)&outAcc[o];
    f4 ohi = *(const f4*)&outAcc[o + 4];
    float ts = tk * sq;
    *(f4*)&outAcc[o]     = olo + ts * wlo;
    *(f4*)&outAcc[o + 4] = ohi + ts * whi;
  }
}

// ---------------- log_softmax rows of 40 ----------------
__global__ __launch_bounds__(256) void k_lsm(float* __restrict__ out) {
  int row = blockIdx.x * 256 + threadIdx.x;
  if (row >= NN) return;
  float* p = out + (size_t)row * CC;
  float v[CC];
#pragma unroll
  for (int i = 0; i < CC / 4; ++i) *(f4*)&v[i * 4] = *(const f4*)&p[i * 4];
  float m = v[0];
#pragma unroll
  for (int i = 1; i < CC; ++i) m = fmaxf(m, v[i]);
  float ssum = 0.f;
#pragma unroll
  for (int i = 0; i < CC; ++i) ssum += expf(v[i] - m);
  float lse = m + logf(ssum);
#pragma unroll
  for (int i = 0; i < CC; ++i) v[i] -= lse;
#pragma unroll
  for (int i = 0; i < CC / 4; ++i) *(f4*)&p[i * 4] = *(f4*)&v[i * 4];
}

extern "C" void kernel_launch(void* const* d_in, const int* in_sizes, int n_in,
                              void* d_out, int out_size, void* d_ws, size_t ws_size,
                              hipStream_t stream) {
  const float* x    = (const float*)d_in[0];
  const int*   ei   = (const int*)d_in[1];
  const float* W1   = (const float*)d_in[2];
  const float* b1   = (const float*)d_in[3];
  const float* W2   = (const float*)d_in[4];
  const float* b2   = (const float*)d_in[5];
  const float* temp = (const float*)d_in[6];
  const int* rowI = ei;
  const int* colI = ei + EE;
  float* out = (float*)d_out;

  char* w = (char*)d_ws;
  auto alloc = [&](size_t bytes) -> void* {
    void* p = (void*)w;
    w += (bytes + 255) & ~(size_t)255;
    return p;
  };
  float* t0    = (float*)alloc((size_t)NN * CC * 4);
  float* t1    = (float*)alloc((size_t)NN * CC * 4);
  int*   deg   = (int*)  alloc((size_t)NN * 4);
  float* dis   = (float*)alloc((size_t)NN * 4);
  float* sqd   = (float*)alloc((size_t)NN * 4);
  float* invd  = (float*)alloc((size_t)NN * 4);
  int*   rs    = (int*)  alloc((size_t)(NN + 1) * 4);
  int*   cur   = (int*)  alloc((size_t)NN * 4);
  int*   perm  = (int*)  alloc((size_t)NN * 4);
  int*   bsums = (int*)  alloc(512 * 4);
  int*   hist  = (int*)  alloc(256 * 4);
  int*   hcnt  = (int*)  alloc(256 * 4);
  unsigned short* W1T = (unsigned short*)alloc((size_t)FIN * HID * 2);
  int*   colS  = (int*)  alloc((size_t)(EE + NN) * 4);   // written concurrently with gemm1 -> own region
  char* big = (char*)alloc((size_t)NN * HID * 4);
  // big region: h1 (51.2MB) during GEMMs; afterwards shadows: sh0 @0, sh1 @+8MB
  float* h1 = (float*)big;
  unsigned short* sh0 = (unsigned short*)big;
  unsigned short* sh1 = (unsigned short*)(big + ((size_t)8 << 20));

  hipMemsetAsync(deg, 0, (size_t)NN * 4, stream);
  hipMemsetAsync(hist, 0, 256 * 4, stream);
  hipMemsetAsync(hcnt, 0, 256 * 4, stream);

  const int NDEG = (EE + 255) / 256;       // 6250
  const int NW1T = FIN * HID / 256;        // 256
  k_dw<<<NDEG + NW1T, 256, 0, stream>>>(rowI, deg, W1, W1T, NDEG);

  k_finalize<<<(NN + 255) / 256, 256, 0, stream>>>(deg, dis, sqd, invd, hist);

  int nb = (NN + 1023) / 1024;             // 98
  k_scan1<<<nb, 256, 0, stream>>>(deg, rs, bsums);
  k_scan2h<<<2, 256, 0, stream>>>(bsums, nb, hist);
  int nb3 = (NN + 255) / 256;              // 391
  k_scan3p<<<2 * nb3, 256, 0, stream>>>(deg, rs, cur, bsums, hist, hcnt, perm, nb3);

  const int NG1 = (NN + 127) / 128;        // 782
  const int NSC = (EE + NN + 1023) / 1024; // 1661
  k_g1sc<<<NG1 + NSC, 256, 0, stream>>>(x, W1T, b1, h1, rowI, colI, cur, colS, NG1);

  k_gemm2<<<(NN * CC) / 256, 256, 0, stream>>>(h1, W2, b2, temp, dis, t0, out);

  // h1 dead: shadows take over the big region
  k_cvt<<<(NN * CC / 4 + 255) / 256, 256, 0, stream>>>(t0, sh0);

  int G = (NN + 47) / 48;                  // 2084
  unsigned short* sh[2] = {sh0, sh1};
  float* tb[2] = {t0, t1};
  k_prop<0><<<G, 256, 0, stream>>>(sh[0], sh[1], t1, out, colS, rs, perm, invd, sqd, temp, 1);
  for (int k = 2; k <= KORD; ++k) {
    k_prop<1><<<G, 256, 0, stream>>>(sh[(k - 1) & 1], sh[k & 1], tb[k & 1], out, colS, rs, perm, invd, sqd, temp, k);
  }

  k_lsm<<<(NN + 255) / 256, 256, 0, stream>>>(out);
}

// Round 6
// 875.842 us; speedup vs baseline: 1.6013x; 1.6013x over previous
//
#include <hip/hip_runtime.h>
#include <hip/hip_bf16.h>
#include <cstdint>
#include <cstddef>

#define NN   100000
#define EE   1600000
#define FIN  512
#define HID  128
#define CC   40
#define KORD 10
#define SHB  96   // bytes per node row in bf16 shadow (40*2=80 data, padded to 96 for 16B alignment)

typedef __attribute__((ext_vector_type(4))) float f4;
typedef __attribute__((ext_vector_type(8))) short short8_t;
typedef __attribute__((ext_vector_type(4))) unsigned int u4;

__device__ __forceinline__ unsigned short cvt_bf16(float f) {
  union { float f; unsigned u; } a; a.f = f;
  unsigned r = a.u + 0x7fffu + ((a.u >> 16) & 1u);   // RNE
  return (unsigned short)(r >> 16);
}
__device__ __forceinline__ unsigned pk_bf(float a, float b) {
  union { float f; unsigned u; } x, y; x.f = a; y.f = b;
  unsigned ra = x.u + 0x7fffu + ((x.u >> 16) & 1u);
  unsigned rb = y.u + 0x7fffu + ((y.u >> 16) & 1u);
  return (ra >> 16) | (rb & 0xffff0000u);
}
// two packed-bf16 words -> 4 floats
__device__ __forceinline__ f4 cvf2(unsigned lo, unsigned hi) {
  union { unsigned u; float f; } a, b, c, d;
  a.u = lo << 16; b.u = lo & 0xffff0000u;
  c.u = hi << 16; d.u = hi & 0xffff0000u;
  f4 r; r.x = a.f; r.y = b.f; r.z = c.f; r.w = d.f; return r;
}

// ---------------- deg count (blocks [0,ndeg)) || W1 bf16 k-tiled transpose ----------------
__global__ __launch_bounds__(256) void k_dw(const int* __restrict__ rowI, int* __restrict__ deg,
                                            const float* __restrict__ W1, unsigned short* __restrict__ W1T,
                                            int ndeg) {
  int b = blockIdx.x;
  if (b < ndeg) {
    int i = b * 256 + threadIdx.x;
    if (i < EE) atomicAdd(&deg[rowI[i]], 1);
  } else {
    int idx = (b - ndeg) * 256 + threadIdx.x;   // 0..65535
    int k = idx >> 7, n = idx & 127;
    W1T[(k >> 5) * 4096 + n * 32 + (k & 31)] = cvt_bf16(W1[idx]);
  }
}

// deg+=1 (self loop); dis/sqd/invd; degree histogram (LDS-aggregated -> low contention)
__global__ __launch_bounds__(256) void k_finalize(int* __restrict__ deg, float* __restrict__ dis,
                                                  float* __restrict__ sqd, float* __restrict__ invd,
                                                  int* __restrict__ hist) {
  __shared__ int lh[256];
  int tid = threadIdx.x;
  lh[tid] = 0;
  __syncthreads();
  int i = blockIdx.x * 256 + tid;
  if (i < NN) {
    int d = deg[i] + 1;
    deg[i] = d;
    float fd = (float)d;
    dis[i]  = rsqrtf(fd);
    sqd[i]  = sqrtf(fd);
    invd[i] = 1.0f / fd;
    atomicAdd(&lh[min(d, 255)], 1);
  }
  __syncthreads();
  if (lh[tid] > 0) atomicAdd(&hist[tid], lh[tid]);
}

// ---------------- exclusive scan over deg ----------------
__global__ __launch_bounds__(256) void k_scan1(const int* __restrict__ cnt, int* __restrict__ excl,
                                               int* __restrict__ bsums) {
  __shared__ int s[256];
  int tid = threadIdx.x;
  int base = blockIdx.x * 1024 + tid * 4;
  int v0 = (base + 0 < NN) ? cnt[base + 0] : 0;
  int v1 = (base + 1 < NN) ? cnt[base + 1] : 0;
  int v2 = (base + 2 < NN) ? cnt[base + 2] : 0;
  int v3 = (base + 3 < NN) ? cnt[base + 3] : 0;
  int tsum = v0 + v1 + v2 + v3;
  s[tid] = tsum;
  __syncthreads();
  for (int off = 1; off < 256; off <<= 1) {
    int t = (tid >= off) ? s[tid - off] : 0;
    __syncthreads();
    if (tid >= off) s[tid] += t;
    __syncthreads();
  }
  int run = s[tid] - tsum;
  if (tid == 255) bsums[blockIdx.x] = s[255];
  if (base + 0 < NN) excl[base + 0] = run; run += v0;
  if (base + 1 < NN) excl[base + 1] = run; run += v1;
  if (base + 2 < NN) excl[base + 2] = run; run += v2;
  if (base + 3 < NN) excl[base + 3] = run;
}

// block0: scan block sums ; block1: exclusive scan hist (in place)
__global__ __launch_bounds__(256) void k_scan2h(int* __restrict__ bsums, int nb, int* __restrict__ hist) {
  __shared__ int s[256];
  int tid = threadIdx.x;
  int* arr = (blockIdx.x == 0) ? bsums : hist;
  int lim  = (blockIdx.x == 0) ? nb : 256;
  int v = (tid < lim) ? arr[tid] : 0;
  s[tid] = v;
  __syncthreads();
  for (int off = 1; off < 256; off <<= 1) {
    int t = (tid >= off) ? s[tid - off] : 0;
    __syncthreads();
    if (tid >= off) s[tid] += t;
    __syncthreads();
  }
  if (tid < lim) arr[tid] = s[tid] - v;
}

// blocks [0,nb3): finish scan (rs, cur) ; blocks [nb3,2*nb3): degree-sort perm (LDS-aggregated)
__global__ __launch_bounds__(256) void k_scan3p(const int* __restrict__ cnt, int* __restrict__ rs,
                                                int* __restrict__ cur, const int* __restrict__ bsums,
                                                const int* __restrict__ hoff, int* __restrict__ gcur,
                                                int* __restrict__ perm, int nb3) {
  int b = blockIdx.x;
  int tid = threadIdx.x;
  if (b < nb3) {
    int i = b * 256 + tid;
    if (i < NN) {
      int v = rs[i] + bsums[i >> 10];
      rs[i] = v;
      cur[i] = v;
      if (i == NN - 1) rs[NN] = v + cnt[i];
    }
  } else {
    __shared__ int lh[256];   // per-degree count in this block
    __shared__ int lb[256];   // global base of this block's chunk per degree
    lh[tid] = 0;
    __syncthreads();
    int i = (b - nb3) * 256 + tid;
    int d = 0, rank = 0;
    bool ok = (i < NN);
    if (ok) {
      d = min(cnt[i], 255);
      rank = atomicAdd(&lh[d], 1);      // rank within block for this degree
    }
    __syncthreads();
    if (lh[tid] > 0) lb[tid] = atomicAdd(&gcur[tid], lh[tid]);  // one atomic per (block,degree)
    __syncthreads();
    if (ok) perm[hoff[d] + lb[d] + rank] = i;
  }
}

// ---------------- CSR scatter: colS holds BYTE offsets (c*96) ----------------
__global__ __launch_bounds__(256) void k_scatter(const int* __restrict__ rowI, const int* __restrict__ colI,
                                                 int* __restrict__ cur, int* __restrict__ colS) {
  int i = blockIdx.x * 256 + threadIdx.x;
  if (i >= EE + NN) return;
  int r, c;
  if (i < EE) { r = rowI[i]; c = colI[i]; }
  else        { r = i - EE;  c = r; }
  int pos = atomicAdd(&cur[r], 1);
  colS[pos] = c * SHB;           // byte offset into bf16 shadow [node][48]
}

// ---------------- GEMM1 (MFMA bf16): h1 = relu(x @ W1 + b1) ----------------
#define LDK 40
__global__ __launch_bounds__(256) void k_gemm1(const float* __restrict__ x, const unsigned short* __restrict__ W1T,
                                               const float* __restrict__ b1, float* __restrict__ h1) {
  __shared__ __align__(16) short As_s[128][LDK];
  __shared__ __align__(16) short Bs_s[128][LDK];
  int tid  = threadIdx.x;
  int wave = tid >> 6, lane = tid & 63;
  int blockRow = blockIdx.x * 128;
  int wr = (wave & 1) * 64, wc = (wave >> 1) * 64;
  int l15 = lane & 15, lk = (lane >> 4) * 8;
  int ar = tid >> 1, ak = (tid & 1) * 16;

  f4 acc[4][4] = {};

  for (int k0 = 0; k0 < FIN; k0 += 32) {
    int gr = blockRow + ar;
    f4 xv0 = {0.f,0.f,0.f,0.f}, xv1 = xv0, xv2 = xv0, xv3 = xv0;
    if (gr < NN) {
      const float* xr = x + (size_t)gr * FIN + k0 + ak;
      xv0 = *(const f4*)&xr[0];
      xv1 = *(const f4*)&xr[4];
      xv2 = *(const f4*)&xr[8];
      xv3 = *(const f4*)&xr[12];
    }
    short8_t p0, p1;
#pragma unroll
    for (int q = 0; q < 4; ++q) {
      p0[q]     = (short)cvt_bf16(xv0[q]);
      p0[q + 4] = (short)cvt_bf16(xv1[q]);
      p1[q]     = (short)cvt_bf16(xv2[q]);
      p1[q + 4] = (short)cvt_bf16(xv3[q]);
    }
    *(short8_t*)&As_s[ar][ak]     = p0;
    *(short8_t*)&As_s[ar][ak + 8] = p1;

    const unsigned short* Wt = W1T + (k0 >> 5) * 4096;
    short8_t q0 = *(const short8_t*)&Wt[tid * 16];
    short8_t q1 = *(const short8_t*)&Wt[tid * 16 + 8];
    int bn = tid >> 1, bkk = (tid & 1) * 16;
    *(short8_t*)&Bs_s[bn][bkk]     = q0;
    *(short8_t*)&Bs_s[bn][bkk + 8] = q1;

    __syncthreads();

    short8_t afr[4], bfr[4];
#pragma unroll
    for (int m = 0; m < 4; ++m) afr[m] = *(const short8_t*)&As_s[wr + m * 16 + l15][lk];
#pragma unroll
    for (int n = 0; n < 4; ++n) bfr[n] = *(const short8_t*)&Bs_s[wc + n * 16 + l15][lk];
#pragma unroll
    for (int m = 0; m < 4; ++m)
#pragma unroll
      for (int n = 0; n < 4; ++n)
        acc[m][n] = __builtin_amdgcn_mfma_f32_16x16x32_bf16(afr[m], bfr[n], acc[m][n], 0, 0, 0);

    __syncthreads();
  }

  float bias[4];
#pragma unroll
  for (int n = 0; n < 4; ++n) bias[n] = b1[wc + n * 16 + l15];
#pragma unroll
  for (int m = 0; m < 4; ++m) {
    int baseRow = blockRow + wr + m * 16 + (lane >> 4) * 4;
#pragma unroll
    for (int n = 0; n < 4; ++n) {
      int col = wc + n * 16 + l15;
#pragma unroll
      for (int r = 0; r < 4; ++r) {
        int grow = baseRow + r;
        if (grow < NN) h1[(size_t)grow * HID + col] = fmaxf(acc[m][n][r] + bias[n], 0.f);
      }
    }
  }
}

// ---------------- GEMM2: out = temp0*Tx0 ; w0 = Tx0 * dis (f32, for cvt) ----------------
__global__ __launch_bounds__(256) void k_gemm2(const float* __restrict__ h1, const float* __restrict__ W2,
                                               const float* __restrict__ b2, const float* __restrict__ temp,
                                               const float* __restrict__ dis,
                                               float* __restrict__ w0, float* __restrict__ outAcc) {
  __shared__ float sW[HID * CC];
  __shared__ float sb[CC];
  int tid = threadIdx.x;
  for (int i = tid; i < HID * CC; i += 256) sW[i] = W2[i];
  if (tid < CC) sb[tid] = b2[tid];
  __syncthreads();
  int gid = blockIdx.x * 256 + tid;
  int row = gid / CC;
  int col = gid - row * CC;
  const float* hr = h1 + (size_t)row * HID;
  float acc = sb[col];
#pragma unroll 8
  for (int k = 0; k < HID; ++k) acc = fmaf(hr[k], sW[k * CC + col], acc);
  outAcc[gid] = temp[0] * acc;
  w0[gid] = acc * dis[row];
}

// ---------------- f32 -> bf16 shadow convert (strided SHB rows, 5 threads/node) ----------------
__global__ __launch_bounds__(256) void k_cvt(const float* __restrict__ v, unsigned short* __restrict__ sh) {
  int i = blockIdx.x * 256 + threadIdx.x;
  if (i >= NN * 5) return;
  int node = i / 5, part = i - node * 5;
  const float* p = v + (size_t)node * CC + part * 8;
  f4 a = *(const f4*)p;
  f4 b = *(const f4*)(p + 4);
  u4 pk;
  pk.x = pk_bf(a.x, a.y); pk.y = pk_bf(a.z, a.w);
  pk.z = pk_bf(b.x, b.y); pk.w = pk_bf(b.z, b.w);
  *(u4*)((char*)sh + (size_t)node * SHB + part * 16) = pk;
}

// ---------------- propagation: 5 lanes/node (aligned 16B gathers), 12 nodes/wave, degree-sorted ----------------
// state is bf16 shadows only: shOut currently holds w_{k-2} (read as prev), overwritten with w_k
// MODE 0: w1 = invd*Sum ; MODE 1: wk = 2*invd*Sum - prev ; both: out += temp[kIdx]*sqd*wk
template <int MODE>
__global__ __launch_bounds__(256) void k_prop(const unsigned short* __restrict__ shIn,
                                              unsigned short* __restrict__ shOut,
                                              float* __restrict__ outAcc,
                                              const int* __restrict__ colS,
                                              const int* __restrict__ rs,
                                              const int* __restrict__ perm,
                                              const float* __restrict__ invd, const float* __restrict__ sqd,
                                              const float* __restrict__ temp, int kIdx) {
  int lane = threadIdx.x & 63;
  int wave = threadIdx.x >> 6;
  int grp  = lane / 5;             // 0..12 (12 -> idle lanes 60..63)
  int fi   = lane - grp * 5;       // 0..4 -> features fi*8 .. fi*8+7
  int nidx = blockIdx.x * 48 + wave * 12 + grp;
  bool active = (grp < 12) && (nidx < NN);
  int node = 0, s = 0, e = 0;
  if (active) { node = perm[nidx]; s = rs[node]; e = rs[node + 1]; }
  const char* base = (const char*)shIn + fi * 16;
  f4 lo0 = {0.f,0.f,0.f,0.f}, hi0 = lo0, lo1 = lo0, hi1 = lo0;
  f4 lo2 = lo0, hi2 = lo0, lo3 = lo0, hi3 = lo0;
  int j = s;
  for (; j + 4 <= e; j += 4) {
    int c0 = colS[j], c1 = colS[j + 1], c2 = colS[j + 2], c3 = colS[j + 3];
    u4 p0 = *(const u4*)(base + c0);
    u4 p1 = *(const u4*)(base + c1);
    u4 p2 = *(const u4*)(base + c2);
    u4 p3 = *(const u4*)(base + c3);
    lo0 += cvf2(p0.x, p0.y); hi0 += cvf2(p0.z, p0.w);
    lo1 += cvf2(p1.x, p1.y); hi1 += cvf2(p1.z, p1.w);
    lo2 += cvf2(p2.x, p2.y); hi2 += cvf2(p2.z, p2.w);
    lo3 += cvf2(p3.x, p3.y); hi3 += cvf2(p3.z, p3.w);
  }
  if (j + 2 <= e) {
    int c0 = colS[j], c1 = colS[j + 1];
    u4 p0 = *(const u4*)(base + c0);
    u4 p1 = *(const u4*)(base + c1);
    lo0 += cvf2(p0.x, p0.y); hi0 += cvf2(p0.z, p0.w);
    lo1 += cvf2(p1.x, p1.y); hi1 += cvf2(p1.z, p1.w);
    j += 2;
  }
  if (j < e) {
    u4 p0 = *(const u4*)(base + colS[j]);
    lo2 += cvf2(p0.x, p0.y); hi2 += cvf2(p0.z, p0.w);
  }

  if (active) {
    f4 slo = (lo0 + lo1) + (lo2 + lo3);
    f4 shi = (hi0 + hi1) + (hi2 + hi3);
    float iv = invd[node];
    float ts = temp[kIdx] * sqd[node];
    char* shp = (char*)shOut + (size_t)node * SHB + fi * 16;
    f4 wlo, whi;
    if (MODE == 0) {
      wlo = iv * slo; whi = iv * shi;
    } else {
      u4 pp = *(const u4*)shp;                 // w_{k-2} (bf16)
      f4 plo = cvf2(pp.x, pp.y), phi = cvf2(pp.z, pp.w);
      wlo = (2.f * iv) * slo - plo;
      whi = (2.f * iv) * shi - phi;
    }
    u4 pk;
    pk.x = pk_bf(wlo.x, wlo.y); pk.y = pk_bf(wlo.z, wlo.w);
    pk.z = pk_bf(whi.x, whi.y); pk.w = pk_bf(whi.z, whi.w);
    *(u4*)shp = pk;
    size_t o = (size_t)node * CC + fi * 8;
    f4 olo = *(const f4*)&outAcc[o];
    f4 ohi = *(const f4*)&outAcc[o + 4];
    *(f4*)&outAcc[o]     = olo + ts * wlo;
    *(f4*)&outAcc[o + 4] = ohi + ts * whi;
  }
}

// ---------------- log_softmax rows of 40 ----------------
__global__ __launch_bounds__(256) void k_lsm(float* __restrict__ out) {
  int row = blockIdx.x * 256 + threadIdx.x;
  if (row >= NN) return;
  float* p = out + (size_t)row * CC;
  float v[CC];
#pragma unroll
  for (int i = 0; i < CC / 4; ++i) *(f4*)&v[i * 4] = *(const f4*)&p[i * 4];
  float m = v[0];
#pragma unroll
  for (int i = 1; i < CC; ++i) m = fmaxf(m, v[i]);
  float ssum = 0.f;
#pragma unroll
  for (int i = 0; i < CC; ++i) ssum += expf(v[i] - m);
  float lse = m + logf(ssum);
#pragma unroll
  for (int i = 0; i < CC; ++i) v[i] -= lse;
#pragma unroll
  for (int i = 0; i < CC / 4; ++i) *(f4*)&p[i * 4] = *(f4*)&v[i * 4];
}

extern "C" void kernel_launch(void* const* d_in, const int* in_sizes, int n_in,
                              void* d_out, int out_size, void* d_ws, size_t ws_size,
                              hipStream_t stream) {
  const float* x    = (const float*)d_in[0];
  const int*   ei   = (const int*)d_in[1];
  const float* W1   = (const float*)d_in[2];
  const float* b1   = (const float*)d_in[3];
  const float* W2   = (const float*)d_in[4];
  const float* b2   = (const float*)d_in[5];
  const float* temp = (const float*)d_in[6];
  const int* rowI = ei;
  const int* colI = ei + EE;
  float* out = (float*)d_out;

  char* w = (char*)d_ws;
  auto alloc = [&](size_t bytes) -> void* {
    void* p = (void*)w;
    w += (bytes + 255) & ~(size_t)255;
    return p;
  };
  float* t0    = (float*)alloc((size_t)NN * CC * 4);     // w0 f32 (gemm2 -> cvt)
  int*   deg   = (int*)  alloc((size_t)NN * 4);
  float* dis   = (float*)alloc((size_t)NN * 4);
  float* sqd   = (float*)alloc((size_t)NN * 4);
  float* invd  = (float*)alloc((size_t)NN * 4);
  int*   rs    = (int*)  alloc((size_t)(NN + 1) * 4);
  int*   cur   = (int*)  alloc((size_t)NN * 4);
  int*   perm  = (int*)  alloc((size_t)NN * 4);
  int*   bsums = (int*)  alloc(512 * 4);
  int*   hist  = (int*)  alloc(256 * 4);
  int*   gcur  = (int*)  alloc(256 * 4);
  unsigned short* W1T = (unsigned short*)alloc((size_t)FIN * HID * 2);
  char* big = (char*)alloc((size_t)NN * HID * 4);
  // big region (51.2MB): h1 during GEMMs; afterwards: sh0 @0 (9.6MB), sh1 @+10MB, colS @+20MB (6.8MB)
  float* h1 = (float*)big;
  unsigned short* sh0 = (unsigned short*)big;
  unsigned short* sh1 = (unsigned short*)(big + ((size_t)10 << 20));
  int*   colS = (int*)(big + ((size_t)20 << 20));

  hipMemsetAsync(deg, 0, (size_t)NN * 4, stream);
  hipMemsetAsync(hist, 0, 256 * 4, stream);
  hipMemsetAsync(gcur, 0, 256 * 4, stream);

  const int NDEG = (EE + 255) / 256;       // 6250
  const int NW1T = FIN * HID / 256;        // 256
  k_dw<<<NDEG + NW1T, 256, 0, stream>>>(rowI, deg, W1, W1T, NDEG);

  k_finalize<<<(NN + 255) / 256, 256, 0, stream>>>(deg, dis, sqd, invd, hist);

  int nb = (NN + 1023) / 1024;             // 98
  k_scan1<<<nb, 256, 0, stream>>>(deg, rs, bsums);
  k_scan2h<<<2, 256, 0, stream>>>(bsums, nb, hist);
  int nb3 = (NN + 255) / 256;              // 391
  k_scan3p<<<2 * nb3, 256, 0, stream>>>(deg, rs, cur, bsums, hist, gcur, perm, nb3);

  k_gemm1<<<(NN + 127) / 128, 256, 0, stream>>>(x, W1T, b1, h1);
  k_gemm2<<<(NN * CC) / 256, 256, 0, stream>>>(h1, W2, b2, temp, dis, t0, out);

  // h1 dead: shadows + colS take over the big region
  k_scatter<<<(EE + NN + 255) / 256, 256, 0, stream>>>(rowI, colI, cur, colS);
  k_cvt<<<(NN * 5 + 255) / 256, 256, 0, stream>>>(t0, sh0);

  int G = (NN + 47) / 48;                  // 2084
  unsigned short* sh[2] = {sh0, sh1};
  // k=1: shIn=sh0 (w0), shOut=sh1 (w1)
  k_prop<0><<<G, 256, 0, stream>>>(sh[0], sh[1], out, colS, rs, perm, invd, sqd, temp, 1);
  // k>=2: shIn=sh[(k-1)&1] (w_{k-1}); shOut=sh[k&1] currently holds w_{k-2} -> overwritten with w_k
  for (int k = 2; k <= KORD; ++k) {
    k_prop<1><<<G, 256, 0, stream>>>(sh[(k - 1) & 1], sh[k & 1], out, colS, rs, perm, invd, sqd, temp, k);
  }

  k_lsm<<<(NN + 255) / 256, 256, 0, stream>>>(out);
}

// Round 7
// 666.673 us; speedup vs baseline: 2.1037x; 1.3138x over previous
//
#include <hip/hip_runtime.h>
#include <hip/hip_bf16.h>
#include <cstdint>
#include <cstddef>

#define NN   100000
#define EE   1600000
#define FIN  512
#define HID  128
#define CC   40
#define KORD 10
#define SHB  80   // bytes per node row in bf16 shadow (40*2; 80%16==0 -> 16B-aligned gathers)

typedef __attribute__((ext_vector_type(4))) float f4;
typedef __attribute__((ext_vector_type(2))) float f2;
typedef __attribute__((ext_vector_type(8))) short short8_t;
typedef __attribute__((ext_vector_type(4))) unsigned int u4;

__device__ __forceinline__ unsigned short cvt_bf16(float f) {
  union { float f; unsigned u; } a; a.f = f;
  unsigned r = a.u + 0x7fffu + ((a.u >> 16) & 1u);   // RNE
  return (unsigned short)(r >> 16);
}
__device__ __forceinline__ unsigned pk_bf(float a, float b) {
  union { float f; unsigned u; } x, y; x.f = a; y.f = b;
  unsigned ra = x.u + 0x7fffu + ((x.u >> 16) & 1u);
  unsigned rb = y.u + 0x7fffu + ((y.u >> 16) & 1u);
  return (ra >> 16) | (rb & 0xffff0000u);
}
// two packed-bf16 words -> 4 floats
__device__ __forceinline__ f4 cvf2(unsigned lo, unsigned hi) {
  union { unsigned u; float f; } a, b, c, d;
  a.u = lo << 16; b.u = lo & 0xffff0000u;
  c.u = hi << 16; d.u = hi & 0xffff0000u;
  f4 r; r.x = a.f; r.y = b.f; r.z = c.f; r.w = d.f; return r;
}

// ---------------- deg count (blocks [0,ndeg)) || W1 bf16 k-tiled transpose ----------------
__global__ __launch_bounds__(256) void k_dw(const int* __restrict__ rowI, int* __restrict__ deg,
                                            const float* __restrict__ W1, unsigned short* __restrict__ W1T,
                                            int ndeg) {
  int b = blockIdx.x;
  if (b < ndeg) {
    int i = b * 256 + threadIdx.x;
    if (i < EE) atomicAdd(&deg[rowI[i]], 1);
  } else {
    int idx = (b - ndeg) * 256 + threadIdx.x;   // 0..65535
    int k = idx >> 7, n = idx & 127;
    W1T[(k >> 5) * 4096 + n * 32 + (k & 31)] = cvt_bf16(W1[idx]);
  }
}

// deg += 1 (self loop); dis = 1/sqrt(deg); sqd = sqrt(deg); invd = 1/deg
__global__ __launch_bounds__(256) void k_finalize(int* __restrict__ deg, float* __restrict__ dis,
                                                  float* __restrict__ sqd, float* __restrict__ invd) {
  int i = blockIdx.x * 256 + threadIdx.x;
  if (i < NN) {
    int d = deg[i] + 1;
    deg[i] = d;
    float fd = (float)d;
    dis[i]  = rsqrtf(fd);
    sqd[i]  = sqrtf(fd);
    invd[i] = 1.0f / fd;
  }
}

// ---------------- exclusive scan over deg ----------------
__global__ __launch_bounds__(256) void k_scan1(const int* __restrict__ cnt, int* __restrict__ excl,
                                               int* __restrict__ bsums) {
  __shared__ int s[256];
  int tid = threadIdx.x;
  int base = blockIdx.x * 1024 + tid * 4;
  int v0 = (base + 0 < NN) ? cnt[base + 0] : 0;
  int v1 = (base + 1 < NN) ? cnt[base + 1] : 0;
  int v2 = (base + 2 < NN) ? cnt[base + 2] : 0;
  int v3 = (base + 3 < NN) ? cnt[base + 3] : 0;
  int tsum = v0 + v1 + v2 + v3;
  s[tid] = tsum;
  __syncthreads();
  for (int off = 1; off < 256; off <<= 1) {
    int t = (tid >= off) ? s[tid - off] : 0;
    __syncthreads();
    if (tid >= off) s[tid] += t;
    __syncthreads();
  }
  int run = s[tid] - tsum;
  if (tid == 255) bsums[blockIdx.x] = s[255];
  if (base + 0 < NN) excl[base + 0] = run; run += v0;
  if (base + 1 < NN) excl[base + 1] = run; run += v1;
  if (base + 2 < NN) excl[base + 2] = run; run += v2;
  if (base + 3 < NN) excl[base + 3] = run;
}

__global__ __launch_bounds__(128) void k_scan2(int* __restrict__ bsums, int nb) {
  __shared__ int s[128];
  int tid = threadIdx.x;
  int v = (tid < nb) ? bsums[tid] : 0;
  s[tid] = v;
  __syncthreads();
  for (int off = 1; off < 128; off <<= 1) {
    int t = (tid >= off) ? s[tid - off] : 0;
    __syncthreads();
    if (tid >= off) s[tid] += t;
    __syncthreads();
  }
  if (tid < nb) bsums[tid] = s[tid] - v;
}

__global__ __launch_bounds__(256) void k_scan3(const int* __restrict__ cnt, int* __restrict__ rs,
                                               int* __restrict__ cur, const int* __restrict__ bsums) {
  int i = blockIdx.x * 256 + threadIdx.x;
  if (i < NN) {
    int v = rs[i] + bsums[i >> 10];
    rs[i] = v;
    cur[i] = v;
    if (i == NN - 1) rs[NN] = v + cnt[i];
  }
}

// ---------------- XCD-sliced CSR scatter ----------------
// 8 row-slices; block b: edge chunk b>>3, keeps only rows of slice b&7.
// With round-robin block->XCD dispatch each slice's colS range (~850KB) stays
// in one XCD L2 -> full lines accumulate before writeback.
#define SLICE_ROWS (NN / 8)          // 12500
#define SC_CHUNK   2048
__global__ __launch_bounds__(256) void k_scatter(const int* __restrict__ rowI, const int* __restrict__ colI,
                                                 int* __restrict__ cur, int* __restrict__ colS) {
  int slice = blockIdx.x & 7;
  int chunk = blockIdx.x >> 3;
  int lo = slice * SLICE_ROWS, hi = lo + SLICE_ROWS;
#pragma unroll
  for (int t = 0; t < SC_CHUNK / 256; ++t) {
    int i = chunk * SC_CHUNK + t * 256 + threadIdx.x;
    if (i < EE + NN) {
      int r = (i < EE) ? rowI[i] : (i - EE);
      if (r >= lo && r < hi) {
        int c = (i < EE) ? colI[i] : r;
        int pos = atomicAdd(&cur[r], 1);
        colS[pos] = c * SHB;         // byte offset into bf16 shadow
      }
    }
  }
}

// ---------------- GEMM1 (MFMA bf16): h1 = relu(x @ W1 + b1) ----------------
#define LDK 40
__global__ __launch_bounds__(256) void k_gemm1(const float* __restrict__ x, const unsigned short* __restrict__ W1T,
                                               const float* __restrict__ b1, float* __restrict__ h1) {
  __shared__ __align__(16) short As_s[128][LDK];
  __shared__ __align__(16) short Bs_s[128][LDK];
  int tid  = threadIdx.x;
  int wave = tid >> 6, lane = tid & 63;
  int blockRow = blockIdx.x * 128;
  int wr = (wave & 1) * 64, wc = (wave >> 1) * 64;
  int l15 = lane & 15, lk = (lane >> 4) * 8;
  int ar = tid >> 1, ak = (tid & 1) * 16;

  f4 acc[4][4] = {};

  for (int k0 = 0; k0 < FIN; k0 += 32) {
    int gr = blockRow + ar;
    f4 xv0 = {0.f,0.f,0.f,0.f}, xv1 = xv0, xv2 = xv0, xv3 = xv0;
    if (gr < NN) {
      const float* xr = x + (size_t)gr * FIN + k0 + ak;
      xv0 = *(const f4*)&xr[0];
      xv1 = *(const f4*)&xr[4];
      xv2 = *(const f4*)&xr[8];
      xv3 = *(const f4*)&xr[12];
    }
    short8_t p0, p1;
#pragma unroll
    for (int q = 0; q < 4; ++q) {
      p0[q]     = (short)cvt_bf16(xv0[q]);
      p0[q + 4] = (short)cvt_bf16(xv1[q]);
      p1[q]     = (short)cvt_bf16(xv2[q]);
      p1[q + 4] = (short)cvt_bf16(xv3[q]);
    }
    *(short8_t*)&As_s[ar][ak]     = p0;
    *(short8_t*)&As_s[ar][ak + 8] = p1;

    const unsigned short* Wt = W1T + (k0 >> 5) * 4096;
    short8_t q0 = *(const short8_t*)&Wt[tid * 16];
    short8_t q1 = *(const short8_t*)&Wt[tid * 16 + 8];
    int bn = tid >> 1, bkk = (tid & 1) * 16;
    *(short8_t*)&Bs_s[bn][bkk]     = q0;
    *(short8_t*)&Bs_s[bn][bkk + 8] = q1;

    __syncthreads();

    short8_t afr[4], bfr[4];
#pragma unroll
    for (int m = 0; m < 4; ++m) afr[m] = *(const short8_t*)&As_s[wr + m * 16 + l15][lk];
#pragma unroll
    for (int n = 0; n < 4; ++n) bfr[n] = *(const short8_t*)&Bs_s[wc + n * 16 + l15][lk];
#pragma unroll
    for (int m = 0; m < 4; ++m)
#pragma unroll
      for (int n = 0; n < 4; ++n)
        acc[m][n] = __builtin_amdgcn_mfma_f32_16x16x32_bf16(afr[m], bfr[n], acc[m][n], 0, 0, 0);

    __syncthreads();
  }

  float bias[4];
#pragma unroll
  for (int n = 0; n < 4; ++n) bias[n] = b1[wc + n * 16 + l15];
#pragma unroll
  for (int m = 0; m < 4; ++m) {
    int baseRow = blockRow + wr + m * 16 + (lane >> 4) * 4;
#pragma unroll
    for (int n = 0; n < 4; ++n) {
      int col = wc + n * 16 + l15;
#pragma unroll
      for (int r = 0; r < 4; ++r) {
        int grow = baseRow + r;
        if (grow < NN) h1[(size_t)grow * HID + col] = fmaxf(acc[m][n][r] + bias[n], 0.f);
      }
    }
  }
}

// ---------------- GEMM2 fused: outAcc = temp0*(h1@W2+b2) ; sh0 = bf16((h1@W2+b2)*dis) ----------------
// 2 cols per thread -> one packed u32 shadow store, one f2 outAcc store.
__global__ __launch_bounds__(256) void k_gemm2(const float* __restrict__ h1, const float* __restrict__ W2,
                                               const float* __restrict__ b2, const float* __restrict__ temp,
                                               const float* __restrict__ dis,
                                               unsigned short* __restrict__ sh0, float* __restrict__ outAcc) {
  __shared__ float sW[HID * CC];
  __shared__ float sb[CC];
  int tid = threadIdx.x;
  for (int i = tid; i < HID * CC; i += 256) sW[i] = W2[i];
  if (tid < CC) sb[tid] = b2[tid];
  __syncthreads();
  int gid = blockIdx.x * 256 + tid;
  if (gid >= NN * 20) return;
  int row = gid / 20;
  int c2  = (gid - row * 20) * 2;      // col pair base: 0,2,..,38
  const float* hr = h1 + (size_t)row * HID;
  float a0 = sb[c2], a1 = sb[c2 + 1];
#pragma unroll 8
  for (int k = 0; k < HID; ++k) {
    float hv = hr[k];
    a0 = fmaf(hv, sW[k * CC + c2], a0);
    a1 = fmaf(hv, sW[k * CC + c2 + 1], a1);
  }
  float t0v = temp[0];
  f2 ov; ov.x = t0v * a0; ov.y = t0v * a1;
  *(f2*)&outAcc[(size_t)row * CC + c2] = ov;
  float dv = dis[row];
  *(unsigned*)((char*)sh0 + (size_t)row * SHB + c2 * 2) = pk_bf(a0 * dv, a1 * dv);
}

// ---------------- propagation: 5 lanes/node (aligned 16B gathers), 12 consecutive nodes/wave ----------------
// bf16-only state: shOut holds w_{k-2} (read as prev), overwritten with w_k
// MODE 0: w1 = invd*Sum ; MODE 1: wk = 2*invd*Sum - prev ; both: out += temp[kIdx]*sqd*wk
template <int MODE>
__global__ __launch_bounds__(256) void k_prop(const unsigned short* __restrict__ shIn,
                                              unsigned short* __restrict__ shOut,
                                              float* __restrict__ outAcc,
                                              const int* __restrict__ colS,
                                              const int* __restrict__ rs,
                                              const float* __restrict__ invd, const float* __restrict__ sqd,
                                              const float* __restrict__ temp, int kIdx) {
  int lane = threadIdx.x & 63;
  int wave = threadIdx.x >> 6;
  int grp  = lane / 5;             // 0..12 (12 -> idle lanes 60..63)
  int fi   = lane - grp * 5;       // 0..4 -> features fi*8 .. fi*8+7
  int node = blockIdx.x * 48 + wave * 12 + grp;
  bool active = (grp < 12) && (node < NN);
  int s = 0, e = 0;
  if (active) { s = rs[node]; e = rs[node + 1]; }
  const char* base = (const char*)shIn + fi * 16;
  f4 lo0 = {0.f,0.f,0.f,0.f}, hi0 = lo0, lo1 = lo0, hi1 = lo0;
  f4 lo2 = lo0, hi2 = lo0, lo3 = lo0, hi3 = lo0;
  int j = s;
  for (; j + 4 <= e; j += 4) {
    int c0 = colS[j], c1 = colS[j + 1], c2 = colS[j + 2], c3 = colS[j + 3];
    u4 p0 = *(const u4*)(base + c0);
    u4 p1 = *(const u4*)(base + c1);
    u4 p2 = *(const u4*)(base + c2);
    u4 p3 = *(const u4*)(base + c3);
    lo0 += cvf2(p0.x, p0.y); hi0 += cvf2(p0.z, p0.w);
    lo1 += cvf2(p1.x, p1.y); hi1 += cvf2(p1.z, p1.w);
    lo2 += cvf2(p2.x, p2.y); hi2 += cvf2(p2.z, p2.w);
    lo3 += cvf2(p3.x, p3.y); hi3 += cvf2(p3.z, p3.w);
  }
  if (j + 2 <= e) {
    int c0 = colS[j], c1 = colS[j + 1];
    u4 p0 = *(const u4*)(base + c0);
    u4 p1 = *(const u4*)(base + c1);
    lo0 += cvf2(p0.x, p0.y); hi0 += cvf2(p0.z, p0.w);
    lo1 += cvf2(p1.x, p1.y); hi1 += cvf2(p1.z, p1.w);
    j += 2;
  }
  if (j < e) {
    u4 p0 = *(const u4*)(base + colS[j]);
    lo2 += cvf2(p0.x, p0.y); hi2 += cvf2(p0.z, p0.w);
  }

  if (active) {
    f4 slo = (lo0 + lo1) + (lo2 + lo3);
    f4 shi = (hi0 + hi1) + (hi2 + hi3);
    float iv = invd[node];
    float ts = temp[kIdx] * sqd[node];
    char* shp = (char*)shOut + (size_t)node * SHB + fi * 16;
    f4 wlo, whi;
    if (MODE == 0) {
      wlo = iv * slo; whi = iv * shi;
    } else {
      u4 pp = *(const u4*)shp;                 // w_{k-2} (bf16)
      f4 plo = cvf2(pp.x, pp.y), phi = cvf2(pp.z, pp.w);
      wlo = (2.f * iv) * slo - plo;
      whi = (2.f * iv) * shi - phi;
    }
    u4 pk;
    pk.x = pk_bf(wlo.x, wlo.y); pk.y = pk_bf(wlo.z, wlo.w);
    pk.z = pk_bf(whi.x, whi.y); pk.w = pk_bf(whi.z, whi.w);
    *(u4*)shp = pk;
    size_t o = (size_t)node * CC + fi * 8;
    f4 olo = *(const f4*)&outAcc[o];
    f4 ohi = *(const f4*)&outAcc[o + 4];
    *(f4*)&outAcc[o]     = olo + ts * wlo;
    *(f4*)&outAcc[o + 4] = ohi + ts * whi;
  }
}

// ---------------- log_softmax rows of 40 ----------------
__global__ __launch_bounds__(256) void k_lsm(float* __restrict__ out) {
  int row = blockIdx.x * 256 + threadIdx.x;
  if (row >= NN) return;
  float* p = out + (size_t)row * CC;
  float v[CC];
#pragma unroll
  for (int i = 0; i < CC / 4; ++i) *(f4*)&v[i * 4] = *(const f4*)&p[i * 4];
  float m = v[0];
#pragma unroll
  for (int i = 1; i < CC; ++i) m = fmaxf(m, v[i]);
  float ssum = 0.f;
#pragma unroll
  for (int i = 0; i < CC; ++i) ssum += expf(v[i] - m);
  float lse = m + logf(ssum);
#pragma unroll
  for (int i = 0; i < CC; ++i) v[i] -= lse;
#pragma unroll
  for (int i = 0; i < CC / 4; ++i) *(f4*)&p[i * 4] = *(f4*)&v[i * 4];
}

extern "C" void kernel_launch(void* const* d_in, const int* in_sizes, int n_in,
                              void* d_out, int out_size, void* d_ws, size_t ws_size,
                              hipStream_t stream) {
  const float* x    = (const float*)d_in[0];
  const int*   ei   = (const int*)d_in[1];
  const float* W1   = (const float*)d_in[2];
  const float* b1   = (const float*)d_in[3];
  const float* W2   = (const float*)d_in[4];
  const float* b2   = (const float*)d_in[5];
  const float* temp = (const float*)d_in[6];
  const int* rowI = ei;
  const int* colI = ei + EE;
  float* out = (float*)d_out;

  char* w = (char*)d_ws;
  auto alloc = [&](size_t bytes) -> void* {
    void* p = (void*)w;
    w += (bytes + 255) & ~(size_t)255;
    return p;
  };
  int*   deg   = (int*)  alloc((size_t)NN * 4);
  float* dis   = (float*)alloc((size_t)NN * 4);
  float* sqd   = (float*)alloc((size_t)NN * 4);
  float* invd  = (float*)alloc((size_t)NN * 4);
  int*   rs    = (int*)  alloc((size_t)(NN + 1) * 4);
  int*   cur   = (int*)  alloc((size_t)NN * 4);
  int*   bsums = (int*)  alloc(512 * 4);
  unsigned short* W1T = (unsigned short*)alloc((size_t)FIN * HID * 2);
  unsigned short* sh0 = (unsigned short*)alloc((size_t)NN * SHB);
  unsigned short* sh1 = (unsigned short*)alloc((size_t)NN * SHB);
  int*   colS  = (int*)  alloc((size_t)(EE + NN) * 4);
  float* h1    = (float*)alloc((size_t)NN * HID * 4);

  hipMemsetAsync(deg, 0, (size_t)NN * 4, stream);

  const int NDEG = (EE + 255) / 256;       // 6250
  const int NW1T = FIN * HID / 256;        // 256
  k_dw<<<NDEG + NW1T, 256, 0, stream>>>(rowI, deg, W1, W1T, NDEG);

  k_finalize<<<(NN + 255) / 256, 256, 0, stream>>>(deg, dis, sqd, invd);

  int nb = (NN + 1023) / 1024;             // 98
  k_scan1<<<nb, 256, 0, stream>>>(deg, rs, bsums);
  k_scan2<<<1, 128, 0, stream>>>(bsums, nb);
  k_scan3<<<(NN + 255) / 256, 256, 0, stream>>>(deg, rs, cur, bsums);

  const int NCH = (EE + NN + SC_CHUNK - 1) / SC_CHUNK;   // 831
  k_scatter<<<8 * NCH, 256, 0, stream>>>(rowI, colI, cur, colS);

  k_gemm1<<<(NN + 127) / 128, 256, 0, stream>>>(x, W1T, b1, h1);
  k_gemm2<<<(NN * 20 + 255) / 256, 256, 0, stream>>>(h1, W2, b2, temp, dis, sh0, out);

  int G = (NN + 47) / 48;                  // 2084
  unsigned short* sh[2] = {sh0, sh1};
  // k=1: shIn=sh0 (w0), shOut=sh1
  k_prop<0><<<G, 256, 0, stream>>>(sh[0], sh[1], out, colS, rs, invd, sqd, temp, 1);
  // k>=2: shIn=sh[(k-1)&1]; shOut=sh[k&1] holds w_{k-2} -> overwritten with w_k
  for (int k = 2; k <= KORD; ++k) {
    k_prop<1><<<G, 256, 0, stream>>>(sh[(k - 1) & 1], sh[k & 1], out, colS, rs, invd, sqd, temp, k);
  }

  k_lsm<<<(NN + 255) / 256, 256, 0, stream>>>(out);
}

// Round 9
// 633.904 us; speedup vs baseline: 2.2125x; 1.0517x over previous
//
#include <hip/hip_runtime.h>
#include <hip/hip_bf16.h>
#include <cstdint>
#include <cstddef>

#define NN   100000
#define EE   1600000
#define FIN  512
#define HID  128
#define CC   40
#define KORD 10
#define SHB  80                      // bytes per node row in bf16 shadow
#define SHSTRIDE ((size_t)NN * SHB)  // 8,000,000 B per shadow buffer

typedef __attribute__((ext_vector_type(4))) float f4;
typedef __attribute__((ext_vector_type(8))) short short8_t;
typedef __attribute__((ext_vector_type(4))) unsigned int u4;

__device__ __forceinline__ unsigned short cvt_bf16(float f) {
  union { float f; unsigned u; } a; a.f = f;
  unsigned r = a.u + 0x7fffu + ((a.u >> 16) & 1u);   // RNE
  return (unsigned short)(r >> 16);
}
__device__ __forceinline__ unsigned pk_bf(float a, float b) {
  union { float f; unsigned u; } x, y; x.f = a; y.f = b;
  unsigned ra = x.u + 0x7fffu + ((x.u >> 16) & 1u);
  unsigned rb = y.u + 0x7fffu + ((y.u >> 16) & 1u);
  return (ra >> 16) | (rb & 0xffff0000u);
}
// two packed-bf16 words -> 4 floats
__device__ __forceinline__ f4 cvf2(unsigned lo, unsigned hi) {
  union { unsigned u; float f; } a, b, c, d;
  a.u = lo << 16; b.u = lo & 0xffff0000u;
  c.u = hi << 16; d.u = hi & 0xffff0000u;
  f4 r; r.x = a.f; r.y = b.f; r.z = c.f; r.w = d.f; return r;
}

// ---------------- deg count (blocks [0,ndeg)) || W1 bf16 k-tiled transpose ----------------
__global__ __launch_bounds__(256) void k_dw(const int* __restrict__ rowI, int* __restrict__ deg,
                                            const float* __restrict__ W1, unsigned short* __restrict__ W1T,
                                            int ndeg) {
  int b = blockIdx.x;
  if (b < ndeg) {
    int i = b * 256 + threadIdx.x;
    if (i < EE) atomicAdd(&deg[rowI[i]], 1);
  } else {
    int idx = (b - ndeg) * 256 + threadIdx.x;   // 0..65535
    int k = idx >> 7, n = idx & 127;
    W1T[(k >> 5) * 4096 + n * 32 + (k & 31)] = cvt_bf16(W1[idx]);
  }
}

// deg += 1 (self loop); dis = 1/sqrt(deg); sqd = sqrt(deg); invd = 1/deg
__global__ __launch_bounds__(256) void k_finalize(int* __restrict__ deg, float* __restrict__ dis,
                                                  float* __restrict__ sqd, float* __restrict__ invd) {
  int i = blockIdx.x * 256 + threadIdx.x;
  if (i < NN) {
    int d = deg[i] + 1;
    deg[i] = d;
    float fd = (float)d;
    dis[i]  = rsqrtf(fd);
    sqd[i]  = sqrtf(fd);
    invd[i] = 1.0f / fd;
  }
}

// ---------------- exclusive scan over deg ----------------
__global__ __launch_bounds__(256) void k_scan1(const int* __restrict__ cnt, int* __restrict__ excl,
                                               int* __restrict__ bsums) {
  __shared__ int s[256];
  int tid = threadIdx.x;
  int base = blockIdx.x * 1024 + tid * 4;
  int v0 = (base + 0 < NN) ? cnt[base + 0] : 0;
  int v1 = (base + 1 < NN) ? cnt[base + 1] : 0;
  int v2 = (base + 2 < NN) ? cnt[base + 2] : 0;
  int v3 = (base + 3 < NN) ? cnt[base + 3] : 0;
  int tsum = v0 + v1 + v2 + v3;
  s[tid] = tsum;
  __syncthreads();
  for (int off = 1; off < 256; off <<= 1) {
    int t = (tid >= off) ? s[tid - off] : 0;
    __syncthreads();
    if (tid >= off) s[tid] += t;
    __syncthreads();
  }
  int run = s[tid] - tsum;
  if (tid == 255) bsums[blockIdx.x] = s[255];
  if (base + 0 < NN) excl[base + 0] = run; run += v0;
  if (base + 1 < NN) excl[base + 1] = run; run += v1;
  if (base + 2 < NN) excl[base + 2] = run; run += v2;
  if (base + 3 < NN) excl[base + 3] = run;
}

__global__ __launch_bounds__(128) void k_scan2(int* __restrict__ bsums, int nb) {
  __shared__ int s[128];
  int tid = threadIdx.x;
  int v = (tid < nb) ? bsums[tid] : 0;
  s[tid] = v;
  __syncthreads();
  for (int off = 1; off < 128; off <<= 1) {
    int t = (tid >= off) ? s[tid - off] : 0;
    __syncthreads();
    if (tid >= off) s[tid] += t;
    __syncthreads();
  }
  if (tid < nb) bsums[tid] = s[tid] - v;
}

__global__ __launch_bounds__(256) void k_scan3(const int* __restrict__ cnt, int* __restrict__ rs,
                                               int* __restrict__ cur, const int* __restrict__ bsums) {
  int i = blockIdx.x * 256 + threadIdx.x;
  if (i < NN) {
    int v = rs[i] + bsums[i >> 10];
    rs[i] = v;
    cur[i] = v;
    if (i == NN - 1) rs[NN] = v + cnt[i];
  }
}

// ---------------- XCD-sliced CSR scatter ----------------
#define SLICE_ROWS (NN / 8)          // 12500
#define SC_CHUNK   2048
__global__ __launch_bounds__(256) void k_scatter(const int* __restrict__ rowI, const int* __restrict__ colI,
                                                 int* __restrict__ cur, int* __restrict__ colS) {
  int slice = blockIdx.x & 7;
  int chunk = blockIdx.x >> 3;
  int lo = slice * SLICE_ROWS, hi = lo + SLICE_ROWS;
#pragma unroll
  for (int t = 0; t < SC_CHUNK / 256; ++t) {
    int i = chunk * SC_CHUNK + t * 256 + threadIdx.x;
    if (i < EE + NN) {
      int r = (i < EE) ? rowI[i] : (i - EE);
      if (r >= lo && r < hi) {
        int c = (i < EE) ? colI[i] : r;
        int pos = atomicAdd(&cur[r], 1);
        colS[pos] = c * SHB;         // byte offset into bf16 shadow
      }
    }
  }
}

// ---------------- GEMM1 (MFMA bf16): h1 = relu(x @ W1 + b1) ----------------
#define LDK 40
__global__ __launch_bounds__(256) void k_gemm1(const float* __restrict__ x, const unsigned short* __restrict__ W1T,
                                               const float* __restrict__ b1, float* __restrict__ h1) {
  __shared__ __align__(16) short As_s[128][LDK];
  __shared__ __align__(16) short Bs_s[128][LDK];
  int tid  = threadIdx.x;
  int wave = tid >> 6, lane = tid & 63;
  int blockRow = blockIdx.x * 128;
  int wr = (wave & 1) * 64, wc = (wave >> 1) * 64;
  int l15 = lane & 15, lk = (lane >> 4) * 8;
  int ar = tid >> 1, ak = (tid & 1) * 16;

  f4 acc[4][4] = {};

  for (int k0 = 0; k0 < FIN; k0 += 32) {
    int gr = blockRow + ar;
    f4 xv0 = {0.f,0.f,0.f,0.f}, xv1 = xv0, xv2 = xv0, xv3 = xv0;
    if (gr < NN) {
      const float* xr = x + (size_t)gr * FIN + k0 + ak;
      xv0 = *(const f4*)&xr[0];
      xv1 = *(const f4*)&xr[4];
      xv2 = *(const f4*)&xr[8];
      xv3 = *(const f4*)&xr[12];
    }
    short8_t p0, p1;
#pragma unroll
    for (int q = 0; q < 4; ++q) {
      p0[q]     = (short)cvt_bf16(xv0[q]);
      p0[q + 4] = (short)cvt_bf16(xv1[q]);
      p1[q]     = (short)cvt_bf16(xv2[q]);
      p1[q + 4] = (short)cvt_bf16(xv3[q]);
    }
    *(short8_t*)&As_s[ar][ak]     = p0;
    *(short8_t*)&As_s[ar][ak + 8] = p1;

    const unsigned short* Wt = W1T + (k0 >> 5) * 4096;
    short8_t q0 = *(const short8_t*)&Wt[tid * 16];
    short8_t q1 = *(const short8_t*)&Wt[tid * 16 + 8];
    int bn = tid >> 1, bkk = (tid & 1) * 16;
    *(short8_t*)&Bs_s[bn][bkk]     = q0;
    *(short8_t*)&Bs_s[bn][bkk + 8] = q1;

    __syncthreads();

    short8_t afr[4], bfr[4];
#pragma unroll
    for (int m = 0; m < 4; ++m) afr[m] = *(const short8_t*)&As_s[wr + m * 16 + l15][lk];
#pragma unroll
    for (int n = 0; n < 4; ++n) bfr[n] = *(const short8_t*)&Bs_s[wc + n * 16 + l15][lk];
#pragma unroll
    for (int m = 0; m < 4; ++m)
#pragma unroll
      for (int n = 0; n < 4; ++n)
        acc[m][n] = __builtin_amdgcn_mfma_f32_16x16x32_bf16(afr[m], bfr[n], acc[m][n], 0, 0, 0);

    __syncthreads();
  }

  float bias[4];
#pragma unroll
  for (int n = 0; n < 4; ++n) bias[n] = b1[wc + n * 16 + l15];
#pragma unroll
  for (int m = 0; m < 4; ++m) {
    int baseRow = blockRow + wr + m * 16 + (lane >> 4) * 4;
#pragma unroll
    for (int n = 0; n < 4; ++n) {
      int col = wc + n * 16 + l15;
#pragma unroll
      for (int r = 0; r < 4; ++r) {
        int grow = baseRow + r;
        if (grow < NN) h1[(size_t)grow * HID + col] = fmaxf(acc[m][n][r] + bias[n], 0.f);
      }
    }
  }
}

// ---------------- GEMM2: sh0 = bf16((h1@W2+b2)*dis)  (w0 shadow only) ----------------
__global__ __launch_bounds__(256) void k_gemm2(const float* __restrict__ h1, const float* __restrict__ W2,
                                               const float* __restrict__ b2, const float* __restrict__ temp,
                                               const float* __restrict__ dis,
                                               unsigned short* __restrict__ sh0) {
  __shared__ float sW[HID * CC];
  __shared__ float sb[CC];
  int tid = threadIdx.x;
  for (int i = tid; i < HID * CC; i += 256) sW[i] = W2[i];
  if (tid < CC) sb[tid] = b2[tid];
  __syncthreads();
  int gid = blockIdx.x * 256 + tid;
  if (gid >= NN * 20) return;
  int row = gid / 20;
  int c2  = (gid - row * 20) * 2;      // col pair base
  const float* hr = h1 + (size_t)row * HID;
  float a0 = sb[c2], a1 = sb[c2 + 1];
#pragma unroll 8
  for (int k = 0; k < HID; ++k) {
    float hv = hr[k];
    a0 = fmaf(hv, sW[k * CC + c2], a0);
    a1 = fmaf(hv, sW[k * CC + c2 + 1], a1);
  }
  float dv = dis[row];
  *(unsigned*)((char*)sh0 + (size_t)row * SHB + c2 * 2) = pk_bf(a0 * dv, a1 * dv);
}

// ---------------- propagation: 5 lanes/node (aligned 16B gathers), 12 consecutive nodes/wave ----------------
// MODE 0: w1 = invd*Sum(sh w0)            -> shOut
// MODE 1: wk = 2*invd*Sum - shPrev(w_{k-2}) -> shOut
template <int MODE>
__global__ __launch_bounds__(256) void k_prop(const unsigned short* __restrict__ shIn,
                                              const unsigned short* __restrict__ shPrev,
                                              unsigned short* __restrict__ shOut,
                                              const int* __restrict__ colS,
                                              const int* __restrict__ rs,
                                              const float* __restrict__ invd) {
  int lane = threadIdx.x & 63;
  int wave = threadIdx.x >> 6;
  int grp  = lane / 5;             // 0..12 (12 -> idle lanes 60..63)
  int fi   = lane - grp * 5;       // 0..4 -> features fi*8 .. fi*8+7
  int node = blockIdx.x * 48 + wave * 12 + grp;
  bool active = (grp < 12) && (node < NN);
  int s = 0, e = 0;
  if (active) { s = rs[node]; e = rs[node + 1]; }
  const char* base = (const char*)shIn + fi * 16;
  f4 lo0 = {0.f,0.f,0.f,0.f}, hi0 = lo0, lo1 = lo0, hi1 = lo0;
  f4 lo2 = lo0, hi2 = lo0, lo3 = lo0, hi3 = lo0;
  int j = s;
  for (; j + 4 <= e; j += 4) {
    int c0 = colS[j], c1 = colS[j + 1], c2 = colS[j + 2], c3 = colS[j + 3];
    u4 p0 = *(const u4*)(base + c0);
    u4 p1 = *(const u4*)(base + c1);
    u4 p2 = *(const u4*)(base + c2);
    u4 p3 = *(const u4*)(base + c3);
    lo0 += cvf2(p0.x, p0.y); hi0 += cvf2(p0.z, p0.w);
    lo1 += cvf2(p1.x, p1.y); hi1 += cvf2(p1.z, p1.w);
    lo2 += cvf2(p2.x, p2.y); hi2 += cvf2(p2.z, p2.w);
    lo3 += cvf2(p3.x, p3.y); hi3 += cvf2(p3.z, p3.w);
  }
  if (j + 2 <= e) {
    int c0 = colS[j], c1 = colS[j + 1];
    u4 p0 = *(const u4*)(base + c0);
    u4 p1 = *(const u4*)(base + c1);
    lo0 += cvf2(p0.x, p0.y); hi0 += cvf2(p0.z, p0.w);
    lo1 += cvf2(p1.x, p1.y); hi1 += cvf2(p1.z, p1.w);
    j += 2;
  }
  if (j < e) {
    u4 p0 = *(const u4*)(base + colS[j]);
    lo2 += cvf2(p0.x, p0.y); hi2 += cvf2(p0.z, p0.w);
  }

  if (active) {
    f4 slo = (lo0 + lo1) + (lo2 + lo3);
    f4 shi = (hi0 + hi1) + (hi2 + hi3);
    float iv = invd[node];
    size_t ro = (size_t)node * SHB + fi * 16;
    f4 wlo, whi;
    if (MODE == 0) {
      wlo = iv * slo; whi = iv * shi;
    } else {
      u4 pp = *(const u4*)((const char*)shPrev + ro);   // w_{k-2} (bf16)
      f4 plo = cvf2(pp.x, pp.y), phi = cvf2(pp.z, pp.w);
      wlo = (2.f * iv) * slo - plo;
      whi = (2.f * iv) * shi - phi;
    }
    u4 pk;
    pk.x = pk_bf(wlo.x, wlo.y); pk.y = pk_bf(wlo.z, wlo.w);
    pk.z = pk_bf(whi.x, whi.y); pk.w = pk_bf(whi.z, whi.w);
    *(u4*)((char*)shOut + ro) = pk;
  }
}

// ---------------- final combine: out = log_softmax( sqd * Sum_k temp[k]*w_k ) ----------------
// 5 lanes/node; 11 linear shadow streams; 5-lane shuffle log_softmax.
__global__ __launch_bounds__(256) void k_comb(const unsigned short* __restrict__ shBase,
                                              float* __restrict__ outF,
                                              const float* __restrict__ sqd,
                                              const float* __restrict__ temp) {
  int lane = threadIdx.x & 63;
  int wave = threadIdx.x >> 6;
  int grp  = lane / 5;
  int fi   = lane - grp * 5;
  int node = blockIdx.x * 48 + wave * 12 + grp;
  if (grp >= 12 || node >= NN) return;

  const char* p = (const char*)shBase + (size_t)node * SHB + fi * 16;
  f4 alo = {0.f,0.f,0.f,0.f}, ahi = alo;
#pragma unroll
  for (int k = 0; k <= KORD; ++k) {
    u4 pp = *(const u4*)(p + (size_t)k * SHSTRIDE);
    float tk = temp[k];
    alo += tk * cvf2(pp.x, pp.y);
    ahi += tk * cvf2(pp.z, pp.w);
  }
  float sq = sqd[node];
  alo *= sq; ahi *= sq;

  int gb = grp * 5;
  float m = fmaxf(fmaxf(fmaxf(alo.x, alo.y), fmaxf(alo.z, alo.w)),
                  fmaxf(fmaxf(ahi.x, ahi.y), fmaxf(ahi.z, ahi.w)));
  float mm = m;
#pragma unroll
  for (int j = 0; j < 5; ++j) mm = fmaxf(mm, __shfl(m, gb + j));
  float ss = expf(alo.x - mm) + expf(alo.y - mm) + expf(alo.z - mm) + expf(alo.w - mm)
           + expf(ahi.x - mm) + expf(ahi.y - mm) + expf(ahi.z - mm) + expf(ahi.w - mm);
  float tot = 0.f;
#pragma unroll
  for (int j = 0; j < 5; ++j) tot += __shfl(ss, gb + j);
  float lse = mm + logf(tot);
  alo -= lse; ahi -= lse;
  size_t o = (size_t)node * CC + fi * 8;
  *(f4*)&outF[o]     = alo;
  *(f4*)&outF[o + 4] = ahi;
}

extern "C" void kernel_launch(void* const* d_in, const int* in_sizes, int n_in,
                              void* d_out, int out_size, void* d_ws, size_t ws_size,
                              hipStream_t stream) {
  const float* x    = (const float*)d_in[0];
  const int*   ei   = (const int*)d_in[1];
  const float* W1   = (const float*)d_in[2];
  const float* b1   = (const float*)d_in[3];
  const float* W2   = (const float*)d_in[4];
  const float* b2   = (const float*)d_in[5];
  const float* temp = (const float*)d_in[6];
  const int* rowI = ei;
  const int* colI = ei + EE;
  float* out = (float*)d_out;

  char* w = (char*)d_ws;
  auto alloc = [&](size_t bytes) -> void* {
    void* p = (void*)w;
    w += (bytes + 255) & ~(size_t)255;
    return p;
  };
  int*   deg   = (int*)  alloc((size_t)NN * 4);
  float* dis   = (float*)alloc((size_t)NN * 4);
  float* sqd   = (float*)alloc((size_t)NN * 4);
  float* invd  = (float*)alloc((size_t)NN * 4);
  int*   rs    = (int*)  alloc((size_t)(NN + 1) * 4);
  int*   cur   = (int*)  alloc((size_t)NN * 4);
  int*   bsums = (int*)  alloc(512 * 4);
  unsigned short* W1T = (unsigned short*)alloc((size_t)FIN * HID * 2);
  unsigned short* shAll = (unsigned short*)alloc(SHSTRIDE * (KORD + 1));   // 88 MB: w0..w10
  int*   colS  = (int*)  alloc((size_t)(EE + NN) * 4);
  float* h1    = (float*)alloc((size_t)NN * HID * 4);

  auto sh = [&](int k) -> unsigned short* {
    return (unsigned short*)((char*)shAll + (size_t)k * SHSTRIDE);
  };

  hipMemsetAsync(deg, 0, (size_t)NN * 4, stream);

  const int NDEG = (EE + 255) / 256;       // 6250
  const int NW1T = FIN * HID / 256;        // 256
  k_dw<<<NDEG + NW1T, 256, 0, stream>>>(rowI, deg, W1, W1T, NDEG);

  k_finalize<<<(NN + 255) / 256, 256, 0, stream>>>(deg, dis, sqd, invd);

  int nb = (NN + 1023) / 1024;             // 98
  k_scan1<<<nb, 256, 0, stream>>>(deg, rs, bsums);
  k_scan2<<<1, 128, 0, stream>>>(bsums, nb);
  k_scan3<<<(NN + 255) / 256, 256, 0, stream>>>(deg, rs, cur, bsums);

  const int NCH = (EE + NN + SC_CHUNK - 1) / SC_CHUNK;   // 831
  k_scatter<<<8 * NCH, 256, 0, stream>>>(rowI, colI, cur, colS);

  k_gemm1<<<(NN + 127) / 128, 256, 0, stream>>>(x, W1T, b1, h1);
  k_gemm2<<<(NN * 20 + 255) / 256, 256, 0, stream>>>(h1, W2, b2, temp, dis, sh(0));

  int G = (NN + 47) / 48;                  // 2084
  // k=1: w1 = invd * A w0
  k_prop<0><<<G, 256, 0, stream>>>(sh(0), sh(0), sh(1), colS, rs, invd);
  // k>=2: wk = 2*invd*A w_{k-1} - w_{k-2}
  for (int k = 2; k <= KORD; ++k) {
    k_prop<1><<<G, 256, 0, stream>>>(sh(k - 1), sh(k - 2), sh(k), colS, rs, invd);
  }

  // final: out = log_softmax( sqd * Sum_k temp[k]*w_k )
  k_comb<<<G, 256, 0, stream>>>(shAll, out, sqd, temp);
}

// Round 10
// 625.773 us; speedup vs baseline: 2.2412x; 1.0130x over previous
//
#include <hip/hip_runtime.h>
#include <hip/hip_bf16.h>
#include <cstdint>
#include <cstddef>

#define NN   100000
#define EE   1600000
#define FIN  512
#define HID  128
#define CC   40
#define KORD 10
#define SHB  80                      // bytes per node row in bf16 shadow
#define SHSTRIDE ((size_t)NN * SHB)  // 8,000,000 B per shadow buffer

typedef __attribute__((ext_vector_type(4))) float f4;
typedef __attribute__((ext_vector_type(8))) short short8_t;
typedef __attribute__((ext_vector_type(4))) unsigned int u4;

__device__ __forceinline__ unsigned short cvt_bf16(float f) {
  union { float f; unsigned u; } a; a.f = f;
  unsigned r = a.u + 0x7fffu + ((a.u >> 16) & 1u);   // RNE
  return (unsigned short)(r >> 16);
}
__device__ __forceinline__ unsigned pk_bf(float a, float b) {
  union { float f; unsigned u; } x, y; x.f = a; y.f = b;
  unsigned ra = x.u + 0x7fffu + ((x.u >> 16) & 1u);
  unsigned rb = y.u + 0x7fffu + ((y.u >> 16) & 1u);
  return (ra >> 16) | (rb & 0xffff0000u);
}
// truncating pack (cheap; used only for gemm1 A-operand)
__device__ __forceinline__ unsigned pk_tr(float a, float b) {
  union { float f; unsigned u; } x, y; x.f = a; y.f = b;
  return (x.u >> 16) | (y.u & 0xffff0000u);
}
// two packed-bf16 words -> 4 floats
__device__ __forceinline__ f4 cvf2(unsigned lo, unsigned hi) {
  union { unsigned u; float f; } a, b, c, d;
  a.u = lo << 16; b.u = lo & 0xffff0000u;
  c.u = hi << 16; d.u = hi & 0xffff0000u;
  f4 r; r.x = a.f; r.y = b.f; r.z = c.f; r.w = d.f; return r;
}

// ---------------- deg count (blocks [0,ndeg)) || W1 bf16 k-tiled transpose ----------------
__global__ __launch_bounds__(256) void k_dw(const int* __restrict__ rowI, int* __restrict__ deg,
                                            const float* __restrict__ W1, unsigned short* __restrict__ W1T,
                                            int ndeg) {
  int b = blockIdx.x;
  if (b < ndeg) {
    int i = b * 256 + threadIdx.x;
    if (i < EE) atomicAdd(&deg[rowI[i]], 1);
  } else {
    int idx = (b - ndeg) * 256 + threadIdx.x;   // 0..65535
    int k = idx >> 7, n = idx & 127;
    W1T[(k >> 5) * 4096 + n * 32 + (k & 31)] = cvt_bf16(W1[idx]);
  }
}

// ---------------- exclusive scan over (deg+1) ----------------
__global__ __launch_bounds__(256) void k_scan1(const int* __restrict__ cnt, int* __restrict__ excl,
                                               int* __restrict__ bsums) {
  __shared__ int s[256];
  int tid = threadIdx.x;
  int base = blockIdx.x * 1024 + tid * 4;
  int v0 = (base + 0 < NN) ? cnt[base + 0] + 1 : 0;
  int v1 = (base + 1 < NN) ? cnt[base + 1] + 1 : 0;
  int v2 = (base + 2 < NN) ? cnt[base + 2] + 1 : 0;
  int v3 = (base + 3 < NN) ? cnt[base + 3] + 1 : 0;
  int tsum = v0 + v1 + v2 + v3;
  s[tid] = tsum;
  __syncthreads();
  for (int off = 1; off < 256; off <<= 1) {
    int t = (tid >= off) ? s[tid - off] : 0;
    __syncthreads();
    if (tid >= off) s[tid] += t;
    __syncthreads();
  }
  int run = s[tid] - tsum;
  if (tid == 255) bsums[blockIdx.x] = s[255];
  if (base + 0 < NN) excl[base + 0] = run; run += v0;
  if (base + 1 < NN) excl[base + 1] = run; run += v1;
  if (base + 2 < NN) excl[base + 2] = run; run += v2;
  if (base + 3 < NN) excl[base + 3] = run;
}

__global__ __launch_bounds__(128) void k_scan2(int* __restrict__ bsums, int nb) {
  __shared__ int s[128];
  int tid = threadIdx.x;
  int v = (tid < nb) ? bsums[tid] : 0;
  s[tid] = v;
  __syncthreads();
  for (int off = 1; off < 128; off <<= 1) {
    int t = (tid >= off) ? s[tid - off] : 0;
    __syncthreads();
    if (tid >= off) s[tid] += t;
    __syncthreads();
  }
  if (tid < nb) bsums[tid] = s[tid] - v;
}

// finish scan (rs, cur) + per-node norm factors (replaces k_finalize)
__global__ __launch_bounds__(256) void k_scan3(const int* __restrict__ cnt, int* __restrict__ rs,
                                               int* __restrict__ cur, const int* __restrict__ bsums,
                                               float* __restrict__ dis, float* __restrict__ sqd,
                                               float* __restrict__ invd) {
  int i = blockIdx.x * 256 + threadIdx.x;
  if (i < NN) {
    int v = rs[i] + bsums[i >> 10];
    rs[i] = v;
    cur[i] = v;
    int d = cnt[i] + 1;
    if (i == NN - 1) rs[NN] = v + d;
    float fd = (float)d;
    dis[i]  = rsqrtf(fd);
    sqd[i]  = sqrtf(fd);
    invd[i] = 1.0f / fd;
  }
}

// ---------------- XCD-sliced CSR scatter ----------------
#define SLICE_ROWS (NN / 8)          // 12500
#define SC_CHUNK   2048
__global__ __launch_bounds__(256) void k_scatter(const int* __restrict__ rowI, const int* __restrict__ colI,
                                                 int* __restrict__ cur, int* __restrict__ colS) {
  int slice = blockIdx.x & 7;
  int chunk = blockIdx.x >> 3;
  int lo = slice * SLICE_ROWS, hi = lo + SLICE_ROWS;
#pragma unroll
  for (int t = 0; t < SC_CHUNK / 256; ++t) {
    int i = chunk * SC_CHUNK + t * 256 + threadIdx.x;
    if (i < EE + NN) {
      int r = (i < EE) ? rowI[i] : (i - EE);
      if (r >= lo && r < hi) {
        int c = (i < EE) ? colI[i] : r;
        int pos = atomicAdd(&cur[r], 1);
        colS[pos] = c * SHB;         // byte offset into bf16 shadow
      }
    }
  }
}

// ---------------- GEMM1 (MFMA bf16): h1 = relu(x @ W1 + b1) ----------------
// A staged as f32 via global_load_lds (linear LDS dest, pre-swizzled global src:
// 16B slot s at row r holds logical slot s^(r&7)); converted to bf16 at fragment read.
#define LDK 40
__global__ __launch_bounds__(256) void k_gemm1(const float* __restrict__ x, const unsigned short* __restrict__ W1T,
                                               const float* __restrict__ b1, float* __restrict__ h1) {
  __shared__ __align__(16) float As_f[128 * 32];    // 16 KB, swizzled rows of 128B
  __shared__ __align__(16) short Bs_s[128][LDK];
  int tid  = threadIdx.x;
  int wave = tid >> 6, lane = tid & 63;
  int blockRow = blockIdx.x * 128;
  int wr = (wave & 1) * 64, wc = (wave >> 1) * 64;
  int l15 = lane & 15, hi4 = lane >> 4;

  // A staging geometry: wave w stages rows w*32..w*32+31; call c covers 8 rows.
  int sr = (wave << 5) + (lane >> 3);    // + c*8 per call
  int sslot = lane & 7;                  // physical 16B slot in row

  f4 acc[4][4] = {};

  for (int k0 = 0; k0 < FIN; k0 += 32) {
    // ---- stage A: 4 global_load_lds calls per wave (f32, width 16) ----
#pragma unroll
    for (int c = 0; c < 4; ++c) {
      int row = sr + c * 8;
      int gr = blockRow + row;
      int lslot = sslot ^ (row & 7);     // pre-swizzled logical slot
      const float* gp = x + (size_t)gr * FIN + k0 + lslot * 4;
      // wave-uniform LDS base; HW scatters lane l -> base + l*16
      float* lp = &As_f[(wave << 10) + (c << 8)];
      if (gr < NN) {
        __builtin_amdgcn_global_load_lds(
            (const __attribute__((address_space(1))) unsigned int*)gp,
            (__attribute__((address_space(3))) unsigned int*)lp, 16, 0, 0);
      }
    }

    // ---- stage B: coalesced pre-converted W1T tile ----
    const unsigned short* Wt = W1T + (k0 >> 5) * 4096;
    short8_t q0 = *(const short8_t*)&Wt[tid * 16];
    short8_t q1 = *(const short8_t*)&Wt[tid * 16 + 8];
    int bn = tid >> 1, bkk = (tid & 1) * 16;
    *(short8_t*)&Bs_s[bn][bkk]     = q0;
    *(short8_t*)&Bs_s[bn][bkk + 8] = q1;

    __syncthreads();

    short8_t afr[4], bfr[4];
#pragma unroll
    for (int m = 0; m < 4; ++m) {
      int row = wr + m * 16 + l15;
      int s0 = (hi4 * 2) ^ (row & 7);
      int s1 = (hi4 * 2 + 1) ^ (row & 7);
      f4 a0 = *(const f4*)&As_f[(row << 5) + s0 * 4];
      f4 a1 = *(const f4*)&As_f[(row << 5) + s1 * 4];
      u4 p;
      p.x = pk_tr(a0.x, a0.y); p.y = pk_tr(a0.z, a0.w);
      p.z = pk_tr(a1.x, a1.y); p.w = pk_tr(a1.z, a1.w);
      afr[m] = *(short8_t*)&p;
    }
#pragma unroll
    for (int n = 0; n < 4; ++n) bfr[n] = *(const short8_t*)&Bs_s[wc + n * 16 + l15][hi4 * 8];
#pragma unroll
    for (int m = 0; m < 4; ++m)
#pragma unroll
      for (int n = 0; n < 4; ++n)
        acc[m][n] = __builtin_amdgcn_mfma_f32_16x16x32_bf16(afr[m], bfr[n], acc[m][n], 0, 0, 0);

    __syncthreads();
  }

  float bias[4];
#pragma unroll
  for (int n = 0; n < 4; ++n) bias[n] = b1[wc + n * 16 + l15];
#pragma unroll
  for (int m = 0; m < 4; ++m) {
    int baseRow = blockRow + wr + m * 16 + hi4 * 4;
#pragma unroll
    for (int n = 0; n < 4; ++n) {
      int col = wc + n * 16 + l15;
#pragma unroll
      for (int r = 0; r < 4; ++r) {
        int grow = baseRow + r;
        if (grow < NN) h1[(size_t)grow * HID + col] = fmaxf(acc[m][n][r] + bias[n], 0.f);
      }
    }
  }
}

// ---------------- GEMM2: sh0 = bf16((h1@W2+b2)*dis)  (w0 shadow only) ----------------
__global__ __launch_bounds__(256) void k_gemm2(const float* __restrict__ h1, const float* __restrict__ W2,
                                               const float* __restrict__ b2, const float* __restrict__ temp,
                                               const float* __restrict__ dis,
                                               unsigned short* __restrict__ sh0) {
  __shared__ float sW[HID * CC];
  __shared__ float sb[CC];
  int tid = threadIdx.x;
  for (int i = tid; i < HID * CC; i += 256) sW[i] = W2[i];
  if (tid < CC) sb[tid] = b2[tid];
  __syncthreads();
  int gid = blockIdx.x * 256 + tid;
  if (gid >= NN * 20) return;
  int row = gid / 20;
  int c2  = (gid - row * 20) * 2;      // col pair base
  const float* hr = h1 + (size_t)row * HID;
  float a0 = sb[c2], a1 = sb[c2 + 1];
#pragma unroll 8
  for (int k = 0; k < HID; ++k) {
    float hv = hr[k];
    a0 = fmaf(hv, sW[k * CC + c2], a0);
    a1 = fmaf(hv, sW[k * CC + c2 + 1], a1);
  }
  float dv = dis[row];
  *(unsigned*)((char*)sh0 + (size_t)row * SHB + c2 * 2) = pk_bf(a0 * dv, a1 * dv);
}

// ---------------- propagation: 5 lanes/node, 12 nodes/wave, 8 gathers in flight ----------------
// MODE 0: w1 = invd*Sum(sh w0)              -> shOut
// MODE 1: wk = 2*invd*Sum - shPrev(w_{k-2}) -> shOut
template <int MODE>
__global__ __launch_bounds__(256) void k_prop(const unsigned short* __restrict__ shIn,
                                              const unsigned short* __restrict__ shPrev,
                                              unsigned short* __restrict__ shOut,
                                              const int* __restrict__ colS,
                                              const int* __restrict__ rs,
                                              const float* __restrict__ invd) {
  int lane = threadIdx.x & 63;
  int wave = threadIdx.x >> 6;
  int grp  = lane / 5;             // 0..12 (12 -> idle lanes 60..63)
  int fi   = lane - grp * 5;       // 0..4 -> features fi*8 .. fi*8+7
  int node = blockIdx.x * 48 + wave * 12 + grp;
  bool active = (grp < 12) && (node < NN);
  int s = 0, e = 0;
  if (active) { s = rs[node]; e = rs[node + 1]; }
  const char* base = (const char*)shIn + fi * 16;
  f4 lo0 = {0.f,0.f,0.f,0.f}, hi0 = lo0, lo1 = lo0, hi1 = lo0;
  f4 lo2 = lo0, hi2 = lo0, lo3 = lo0, hi3 = lo0;
  int j = s;
  for (; j + 8 <= e; j += 8) {
    int c0 = colS[j],     c1 = colS[j + 1], c2 = colS[j + 2], c3 = colS[j + 3];
    int c4 = colS[j + 4], c5 = colS[j + 5], c6 = colS[j + 6], c7 = colS[j + 7];
    u4 p0 = *(const u4*)(base + c0);
    u4 p1 = *(const u4*)(base + c1);
    u4 p2 = *(const u4*)(base + c2);
    u4 p3 = *(const u4*)(base + c3);
    u4 p4 = *(const u4*)(base + c4);
    u4 p5 = *(const u4*)(base + c5);
    u4 p6 = *(const u4*)(base + c6);
    u4 p7 = *(const u4*)(base + c7);
    lo0 += cvf2(p0.x, p0.y); hi0 += cvf2(p0.z, p0.w);
    lo1 += cvf2(p1.x, p1.y); hi1 += cvf2(p1.z, p1.w);
    lo2 += cvf2(p2.x, p2.y); hi2 += cvf2(p2.z, p2.w);
    lo3 += cvf2(p3.x, p3.y); hi3 += cvf2(p3.z, p3.w);
    lo0 += cvf2(p4.x, p4.y); hi0 += cvf2(p4.z, p4.w);
    lo1 += cvf2(p5.x, p5.y); hi1 += cvf2(p5.z, p5.w);
    lo2 += cvf2(p6.x, p6.y); hi2 += cvf2(p6.z, p6.w);
    lo3 += cvf2(p7.x, p7.y); hi3 += cvf2(p7.z, p7.w);
  }
  if (j + 4 <= e) {
    int c0 = colS[j], c1 = colS[j + 1], c2 = colS[j + 2], c3 = colS[j + 3];
    u4 p0 = *(const u4*)(base + c0);
    u4 p1 = *(const u4*)(base + c1);
    u4 p2 = *(const u4*)(base + c2);
    u4 p3 = *(const u4*)(base + c3);
    lo0 += cvf2(p0.x, p0.y); hi0 += cvf2(p0.z, p0.w);
    lo1 += cvf2(p1.x, p1.y); hi1 += cvf2(p1.z, p1.w);
    lo2 += cvf2(p2.x, p2.y); hi2 += cvf2(p2.z, p2.w);
    lo3 += cvf2(p3.x, p3.y); hi3 += cvf2(p3.z, p3.w);
    j += 4;
  }
  if (j + 2 <= e) {
    u4 p0 = *(const u4*)(base + colS[j]);
    u4 p1 = *(const u4*)(base + colS[j + 1]);
    lo0 += cvf2(p0.x, p0.y); hi0 += cvf2(p0.z, p0.w);
    lo1 += cvf2(p1.x, p1.y); hi1 += cvf2(p1.z, p1.w);
    j += 2;
  }
  if (j < e) {
    u4 p0 = *(const u4*)(base + colS[j]);
    lo2 += cvf2(p0.x, p0.y); hi2 += cvf2(p0.z, p0.w);
  }

  if (active) {
    f4 slo = (lo0 + lo1) + (lo2 + lo3);
    f4 shi = (hi0 + hi1) + (hi2 + hi3);
    float iv = invd[node];
    size_t ro = (size_t)node * SHB + fi * 16;
    f4 wlo, whi;
    if (MODE == 0) {
      wlo = iv * slo; whi = iv * shi;
    } else {
      u4 pp = *(const u4*)((const char*)shPrev + ro);   // w_{k-2} (bf16)
      f4 plo = cvf2(pp.x, pp.y), phi = cvf2(pp.z, pp.w);
      wlo = (2.f * iv) * slo - plo;
      whi = (2.f * iv) * shi - phi;
    }
    u4 pk;
    pk.x = pk_bf(wlo.x, wlo.y); pk.y = pk_bf(wlo.z, wlo.w);
    pk.z = pk_bf(whi.x, whi.y); pk.w = pk_bf(whi.z, whi.w);
    *(u4*)((char*)shOut + ro) = pk;
  }
}

// ---------------- final combine: out = log_softmax( sqd * Sum_k temp[k]*w_k ) ----------------
__global__ __launch_bounds__(256) void k_comb(const unsigned short* __restrict__ shBase,
                                              float* __restrict__ outF,
                                              const float* __restrict__ sqd,
                                              const float* __restrict__ temp) {
  int lane = threadIdx.x & 63;
  int wave = threadIdx.x >> 6;
  int grp  = lane / 5;
  int fi   = lane - grp * 5;
  int node = blockIdx.x * 48 + wave * 12 + grp;
  if (grp >= 12 || node >= NN) return;

  const char* p = (const char*)shBase + (size_t)node * SHB + fi * 16;
  f4 alo = {0.f,0.f,0.f,0.f}, ahi = alo;
#pragma unroll
  for (int k = 0; k <= KORD; ++k) {
    u4 pp = *(const u4*)(p + (size_t)k * SHSTRIDE);
    float tk = temp[k];
    alo += tk * cvf2(pp.x, pp.y);
    ahi += tk * cvf2(pp.z, pp.w);
  }
  float sq = sqd[node];
  alo *= sq; ahi *= sq;

  int gb = grp * 5;
  float m = fmaxf(fmaxf(fmaxf(alo.x, alo.y), fmaxf(alo.z, alo.w)),
                  fmaxf(fmaxf(ahi.x, ahi.y), fmaxf(ahi.z, ahi.w)));
  float mm = m;
#pragma unroll
  for (int j = 0; j < 5; ++j) mm = fmaxf(mm, __shfl(m, gb + j));
  float ss = expf(alo.x - mm) + expf(alo.y - mm) + expf(alo.z - mm) + expf(alo.w - mm)
           + expf(ahi.x - mm) + expf(ahi.y - mm) + expf(ahi.z - mm) + expf(ahi.w - mm);
  float tot = 0.f;
#pragma unroll
  for (int j = 0; j < 5; ++j) tot += __shfl(ss, gb + j);
  float lse = mm + logf(tot);
  alo -= lse; ahi -= lse;
  size_t o = (size_t)node * CC + fi * 8;
  *(f4*)&outF[o]     = alo;
  *(f4*)&outF[o + 4] = ahi;
}

extern "C" void kernel_launch(void* const* d_in, const int* in_sizes, int n_in,
                              void* d_out, int out_size, void* d_ws, size_t ws_size,
                              hipStream_t stream) {
  const float* x    = (const float*)d_in[0];
  const int*   ei   = (const int*)d_in[1];
  const float* W1   = (const float*)d_in[2];
  const float* b1   = (const float*)d_in[3];
  const float* W2   = (const float*)d_in[4];
  const float* b2   = (const float*)d_in[5];
  const float* temp = (const float*)d_in[6];
  const int* rowI = ei;
  const int* colI = ei + EE;
  float* out = (float*)d_out;

  char* w = (char*)d_ws;
  auto alloc = [&](size_t bytes) -> void* {
    void* p = (void*)w;
    w += (bytes + 255) & ~(size_t)255;
    return p;
  };
  int*   deg   = (int*)  alloc((size_t)NN * 4);
  float* dis   = (float*)alloc((size_t)NN * 4);
  float* sqd   = (float*)alloc((size_t)NN * 4);
  float* invd  = (float*)alloc((size_t)NN * 4);
  int*   rs    = (int*)  alloc((size_t)(NN + 1) * 4);
  int*   cur   = (int*)  alloc((size_t)NN * 4);
  int*   bsums = (int*)  alloc(512 * 4);
  unsigned short* W1T = (unsigned short*)alloc((size_t)FIN * HID * 2);
  unsigned short* shAll = (unsigned short*)alloc(SHSTRIDE * (KORD + 1));   // 88 MB: w0..w10
  int*   colS  = (int*)  alloc((size_t)(EE + NN) * 4);
  float* h1    = (float*)alloc((size_t)NN * HID * 4);

  auto sh = [&](int k) -> unsigned short* {
    return (unsigned short*)((char*)shAll + (size_t)k * SHSTRIDE);
  };

  hipMemsetAsync(deg, 0, (size_t)NN * 4, stream);

  const int NDEG = (EE + 255) / 256;       // 6250
  const int NW1T = FIN * HID / 256;        // 256
  k_dw<<<NDEG + NW1T, 256, 0, stream>>>(rowI, deg, W1, W1T, NDEG);

  int nb = (NN + 1023) / 1024;             // 98
  k_scan1<<<nb, 256, 0, stream>>>(deg, rs, bsums);
  k_scan2<<<1, 128, 0, stream>>>(bsums, nb);
  k_scan3<<<(NN + 255) / 256, 256, 0, stream>>>(deg, rs, cur, bsums, dis, sqd, invd);

  const int NCH = (EE + NN + SC_CHUNK - 1) / SC_CHUNK;   // 831
  k_scatter<<<8 * NCH, 256, 0, stream>>>(rowI, colI, cur, colS);

  k_gemm1<<<(NN + 127) / 128, 256, 0, stream>>>(x, W1T, b1, h1);
  k_gemm2<<<(NN * 20 + 255) / 256, 256, 0, stream>>>(h1, W2, b2, temp, dis, sh(0));

  int G = (NN + 47) / 48;                  // 2084
  // k=1: w1 = invd * A w0
  k_prop<0><<<G, 256, 0, stream>>>(sh(0), sh(0), sh(1), colS, rs, invd);
  // k>=2: wk = 2*invd*A w_{k-1} - w_{k-2}
  for (int k = 2; k <= KORD; ++k) {
    k_prop<1><<<G, 256, 0, stream>>>(sh(k - 1), sh(k - 2), sh(k), colS, rs, invd);
  }

  // final: out = log_softmax( sqd * Sum_k temp[k]*w_k )
  k_comb<<<G, 256, 0, stream>>>(shAll, out, sqd, temp);
}